// Round 1
// baseline (12266.638 us; speedup 1.0000x reference)
//
#include <hip/hip_runtime.h>

#define BB 4
#define CC 128
#define HH 256
#define WW 256
#define HWSZ 65536
#define H2 128
#define W2 128
#define L4SZ 16384
#define MIDC 256
#define NHEADS 8

// ---------------- K1: LayerNorm over channel dim (NCHW), one thread per pixel
__global__ __launch_bounds__(256) void k_ln1(const float* __restrict__ x,
                                             const float* __restrict__ w,
                                             const float* __restrict__ b,
                                             float* __restrict__ out) {
  int idx = blockIdx.x * 256 + threadIdx.x;  // B*HW threads
  int bi = idx >> 16;
  int p  = idx & 65535;
  const float* xp = x + (bi * CC) * HWSZ + p;
  float s = 0.f, s2 = 0.f;
  for (int c = 0; c < CC; c++) { float v = xp[c * HWSZ]; s += v; s2 += v * v; }
  float mu  = s * (1.f / CC);
  float rstd = rsqrtf(s2 * (1.f / CC) - mu * mu + 1e-5f);
  float* op = out + (bi * CC) * HWSZ + p;
  for (int c = 0; c < CC; c++)
    op[c * HWSZ] = (xp[c * HWSZ] - mu) * rstd * w[c] + b[c];
}

// ---------------- K2: depthwise 3x3 stride-2 conv, reflect pad 1 (q and a1)
__global__ __launch_bounds__(256) void k_dws2(const float* __restrict__ in,
                                              const float* __restrict__ w,
                                              float* __restrict__ out) {
  int idx = blockIdx.x * 256 + threadIdx.x;  // B*C*L4
  int xo = idx & (W2 - 1);
  int t = idx >> 7;
  int yo = t & (H2 - 1); t >>= 7;
  int c = t & (CC - 1);
  int bi = t >> 7;
  const float* ip = in + (bi * CC + c) * HWSZ;
  const float* wp = w + c * 9;
  float acc = 0.f;
#pragma unroll
  for (int dy = 0; dy < 3; dy++) {
    int r = 2 * yo + dy - 1; r = r < 0 ? -r : r;  // reflect(-1)=1; max 255
#pragma unroll
    for (int dx = 0; dx < 3; dx++) {
      int cc2 = 2 * xo + dx - 1; cc2 = cc2 < 0 ? -cc2 : cc2;
      acc += wp[dy * 3 + dx] * ip[r * WW + cc2];
    }
  }
  out[idx] = acc;
}

// ---------------- K3: dense 3x3 stride-2 conv 128->128, reflect pad (k)
// block = 256 thr, computes 8x8 output pixels x all 128 co; ci chunked by 8
__global__ __launch_bounds__(256) void k_kconv(const float* __restrict__ xn,
                                               const float* __restrict__ kw,
                                               float* __restrict__ outk) {
  __shared__ float tile[8][289];        // 8 ci x 17x17
  __shared__ float wlds[128][8][9];     // all co x 8 ci x 9 taps
  int blk = blockIdx.x;
  int bx = blk & 15;
  int by = (blk >> 4) & 15;
  int bi = blk >> 8;
  int r0 = by * 16 - 1, c0 = bx * 16 - 1;
  int px = threadIdx.x & 63;
  int co0 = ((__builtin_amdgcn_readfirstlane((int)threadIdx.x)) >> 6) << 5;
  int py = px >> 3, pxx = px & 7;
  float acc[32];
#pragma unroll
  for (int j = 0; j < 32; j++) acc[j] = 0.f;
  for (int ci0 = 0; ci0 < CC; ci0 += 8) {
    __syncthreads();
    for (int i = threadIdx.x; i < 8 * 289; i += 256) {
      int ci = i / 289, rc = i % 289;
      int rr = rc / 17, ccx = rc % 17;
      int gr = r0 + rr; gr = gr < 0 ? -gr : gr;
      int gc = c0 + ccx; gc = gc < 0 ? -gc : gc;
      tile[ci][rc] = xn[(bi * CC + ci0 + ci) * HWSZ + gr * WW + gc];
    }
    for (int i = threadIdx.x; i < 128 * 8 * 9; i += 256) {
      int co = i / 72, r = i % 72, ci = r / 9, tt = r % 9;
      wlds[co][ci][tt] = kw[(co * CC + ci0 + ci) * 9 + tt];
    }
    __syncthreads();
#pragma unroll
    for (int ci = 0; ci < 8; ci++) {
      int base = 2 * py * 17 + 2 * pxx;
      float v0 = tile[ci][base],      v1 = tile[ci][base + 1],  v2 = tile[ci][base + 2];
      float v3 = tile[ci][base + 17], v4 = tile[ci][base + 18], v5 = tile[ci][base + 19];
      float v6 = tile[ci][base + 34], v7 = tile[ci][base + 35], v8 = tile[ci][base + 36];
#pragma unroll
      for (int j = 0; j < 32; j++) {
        const float* wp = &wlds[co0 + j][ci][0];
        acc[j] += wp[0] * v0 + wp[1] * v1 + wp[2] * v2 + wp[3] * v3 + wp[4] * v4 +
                  wp[5] * v5 + wp[6] * v6 + wp[7] * v7 + wp[8] * v8;
      }
    }
  }
  int oy = by * 8 + py, ox = bx * 8 + pxx;
#pragma unroll
  for (int j = 0; j < 32; j++)
    outk[(bi * CC + co0 + j) * L4SZ + oy * W2 + ox] = acc[j];
}

// ---------------- K4: 1x1 conv 128->128 then * illu (v)
__global__ __launch_bounds__(256) void k_v1x1(const float* __restrict__ xn,
                                              const float* __restrict__ vw,
                                              const float* __restrict__ illu,
                                              float* __restrict__ v) {
  __shared__ float t[CC][64];
  int blk = blockIdx.x;
  int bi = blk >> 10;            // HW/64 = 1024 blocks per batch
  int p0 = (blk & 1023) * 64;
  for (int i = threadIdx.x; i < CC * 64; i += 256) {
    int ci = i >> 6, px = i & 63;
    t[ci][px] = xn[(bi * CC + ci) * HWSZ + p0 + px];
  }
  __syncthreads();
  int px = threadIdx.x & 63;
  int co0 = ((__builtin_amdgcn_readfirstlane((int)threadIdx.x)) >> 6) << 5;
  float acc[32];
#pragma unroll
  for (int j = 0; j < 32; j++) acc[j] = 0.f;
  for (int ci = 0; ci < CC; ci++) {
    float in = t[ci][px];
#pragma unroll
    for (int j = 0; j < 32; j++) acc[j] += vw[(co0 + j) * CC + ci] * in;
  }
#pragma unroll
  for (int j = 0; j < 32; j++) {
    int gi = (bi * CC + co0 + j) * HWSZ + p0 + px;
    v[gi] = acc[j] * illu[gi];
  }
}

// ---------------- K5: 1x1 conv 128->64 + bias (a2)
__global__ __launch_bounds__(256) void k_a2(const float* __restrict__ a1,
                                            const float* __restrict__ w,
                                            const float* __restrict__ bias,
                                            float* __restrict__ ab) {
  __shared__ float t[CC][64];
  int blk = blockIdx.x;
  int bi = blk >> 8;             // L4/64 = 256 blocks per batch
  int p0 = (blk & 255) * 64;
  for (int i = threadIdx.x; i < CC * 64; i += 256) {
    int ci = i >> 6, px = i & 63;
    t[ci][px] = a1[(bi * CC + ci) * L4SZ + p0 + px];
  }
  __syncthreads();
  int px = threadIdx.x & 63;
  int co0 = ((__builtin_amdgcn_readfirstlane((int)threadIdx.x)) >> 6) << 4;  // *16
  float acc[16];
#pragma unroll
  for (int j = 0; j < 16; j++) acc[j] = 0.f;
  for (int ci = 0; ci < CC; ci++) {
    float in = t[ci][px];
#pragma unroll
    for (int j = 0; j < 16; j++) acc[j] += w[(co0 + j) * CC + ci] * in;
  }
#pragma unroll
  for (int j = 0; j < 16; j++)
    ab[(bi * 64 + co0 + j) * L4SZ + p0 + px] = acc[j] + bias[co0 + j];
}

// ---------------- K6: attention logits (l2norm folded in) + softmax
__global__ __launch_bounds__(256) void k_attn(const float* __restrict__ q,
                                              const float* __restrict__ k,
                                              const float* __restrict__ a,
                                              const float* __restrict__ tA,
                                              const float* __restrict__ tV,
                                              float* __restrict__ attnA,
                                              float* __restrict__ attnK) {
  int bh = blockIdx.x;
  int bi = bh >> 3, h = bh & 7;
  const float* qb = q + (bi * CC + h * 16) * L4SZ;
  const float* kb = k + (bi * CC + h * 16) * L4SZ;
  const float* ab = a + (bi * 64 + h * 8) * L4SZ;
  __shared__ float dots[296];
  int wave = threadIdx.x >> 6, lane = threadIdx.x & 63;
  for (int d = wave; d < 296; d += 4) {
    const float *ra, *rb;
    if (d < 128)      { ra = qb + (d >> 3) * L4SZ; rb = ab + (d & 7) * L4SZ; }
    else if (d < 256) { int dd = d - 128; ra = ab + (dd >> 4) * L4SZ; rb = kb + (dd & 15) * L4SZ; }
    else if (d < 272) { ra = qb + (d - 256) * L4SZ; rb = ra; }
    else if (d < 280) { ra = ab + (d - 272) * L4SZ; rb = ra; }
    else              { ra = kb + (d - 280) * L4SZ; rb = ra; }
    float s = 0.f;
    for (int l = lane; l < L4SZ; l += 64) s += ra[l] * rb[l];
#pragma unroll
    for (int off = 32; off > 0; off >>= 1) s += __shfl_down(s, off);
    if (lane == 0) dots[d] = s;
  }
  __syncthreads();
  float ta = tA[h], tv = tV[h];
  if (threadIdx.x < 16) {
    int c = threadIdx.x;
    float nq = fmaxf(sqrtf(dots[256 + c]), 1e-12f);
    float lg[8]; float m = -1e30f;
#pragma unroll
    for (int e = 0; e < 8; e++) {
      float na = fmaxf(sqrtf(dots[272 + e]), 1e-12f);
      lg[e] = dots[c * 8 + e] / (nq * na) * ta;
      m = fmaxf(m, lg[e]);
    }
    float sum = 0.f;
#pragma unroll
    for (int e = 0; e < 8; e++) { lg[e] = expf(lg[e] - m); sum += lg[e]; }
    float inv = 1.f / sum;
#pragma unroll
    for (int e = 0; e < 8; e++) attnA[(bh * 16 + c) * 8 + e] = lg[e] * inv;
  } else if (threadIdx.x < 24) {
    int e = threadIdx.x - 16;
    float na = fmaxf(sqrtf(dots[272 + e]), 1e-12f);
    float lg[16]; float m = -1e30f;
#pragma unroll
    for (int c = 0; c < 16; c++) {
      float nk = fmaxf(sqrtf(dots[280 + c]), 1e-12f);
      lg[c] = dots[128 + e * 16 + c] / (na * nk) * tv;
      m = fmaxf(m, lg[c]);
    }
    float sum = 0.f;
#pragma unroll
    for (int c = 0; c < 16; c++) { lg[c] = expf(lg[c] - m); sum += lg[c]; }
    float inv = 1.f / sum;
#pragma unroll
    for (int c = 0; c < 16; c++) attnK[(bh * 8 + e) * 16 + c] = lg[c] * inv;
  }
}

// ---------------- K7: W_eff[b][co][h*8+d] = sum_c po[co][h*16+c]*attnA[b,h,c,d]
__global__ __launch_bounds__(256) void k_weff(const float* __restrict__ po,
                                              const float* __restrict__ attnA,
                                              float* __restrict__ weff) {
  int bi = blockIdx.x;
  for (int o = threadIdx.x; o < 128 * 64; o += 256) {
    int co = o >> 6, hd = o & 63, h = hd >> 3, d = hd & 7;
    float s = 0.f;
#pragma unroll
    for (int c = 0; c < 16; c++)
      s += po[co * CC + h * 16 + c] * attnA[((bi * 8 + h) * 16 + c) * 8 + d];
    weff[bi * 8192 + o] = s;
  }
}

// ---------------- K8: out_v[b,hd,m] = sum_c attnK[b,h,d,c]*v[b,h*16+c,m]
__global__ __launch_bounds__(256) void k_outv(const float* __restrict__ attnK,
                                              const float* __restrict__ v,
                                              float* __restrict__ outv) {
  __shared__ float ak[8][8][16];
  int idx = blockIdx.x * 256 + threadIdx.x;  // B*HW
  int bi = idx >> 16;
  int m  = idx & 65535;
  for (int i = threadIdx.x; i < 1024; i += 256)
    ((float*)ak)[i] = attnK[bi * 1024 + i];
  __syncthreads();
  float acc[64];
#pragma unroll
  for (int j = 0; j < 64; j++) acc[j] = 0.f;
  const float* vb = v + bi * CC * HWSZ + m;
#pragma unroll
  for (int h = 0; h < 8; h++)
#pragma unroll
    for (int c = 0; c < 16; c++) {
      float vv = vb[(h * 16 + c) * HWSZ];
#pragma unroll
      for (int d = 0; d < 8; d++) acc[h * 8 + d] += ak[h][d][c] * vv;
    }
  float* ob = outv + bi * 64 * HWSZ + m;
#pragma unroll
  for (int hd = 0; hd < 64; hd++) ob[hd * HWSZ] = acc[hd];
}

// ---------------- K9: x2 = x + W_eff @ out_v   (GEMM M=128,K=64 per b)
__global__ __launch_bounds__(256) void k_x2(const float* __restrict__ x,
                                            const float* __restrict__ weff,
                                            const float* __restrict__ outv,
                                            float* __restrict__ x2) {
  __shared__ float t[64][64];
  __shared__ float wsm[128][64];
  int blk = blockIdx.x;
  int bi = blk >> 10;
  int p0 = (blk & 1023) * 64;
  for (int i = threadIdx.x; i < 4096; i += 256) {
    int hd = i >> 6, px = i & 63;
    t[hd][px] = outv[(bi * 64 + hd) * HWSZ + p0 + px];
  }
  for (int i = threadIdx.x; i < 8192; i += 256)
    ((float*)wsm)[i] = weff[bi * 8192 + i];
  __syncthreads();
  int px = threadIdx.x & 63;
  int co0 = ((__builtin_amdgcn_readfirstlane((int)threadIdx.x)) >> 6) << 5;
  float acc[32];
#pragma unroll
  for (int j = 0; j < 32; j++) acc[j] = 0.f;
  for (int kk = 0; kk < 64; kk++) {
    float ov = t[kk][px];
#pragma unroll
    for (int j = 0; j < 32; j++) acc[j] += wsm[co0 + j][kk] * ov;
  }
#pragma unroll
  for (int j = 0; j < 32; j++) {
    int gi = (bi * CC + co0 + j) * HWSZ + p0 + px;
    x2[gi] = x[gi] + acc[j];
  }
}

// ---------------- K10: LN2 + p1 (1x1 conv 128->256 + bias), per batch
__global__ __launch_bounds__(256) void k_ln2p1(const float* __restrict__ x2,
                                               const float* __restrict__ lnw,
                                               const float* __restrict__ lnb,
                                               const float* __restrict__ p1w,
                                               const float* __restrict__ p1b,
                                               float* __restrict__ y1, int bi) {
  __shared__ float t[CC][64];
  __shared__ float smu[64], srs[64];
  int p0 = blockIdx.x * 64;
  for (int i = threadIdx.x; i < CC * 64; i += 256) {
    int ci = i >> 6, px = i & 63;
    t[ci][px] = x2[(bi * CC + ci) * HWSZ + p0 + px];
  }
  __syncthreads();
  if (threadIdx.x < 64) {
    int px = threadIdx.x;
    float s = 0.f, s2 = 0.f;
    for (int ci = 0; ci < CC; ci++) { float v = t[ci][px]; s += v; s2 += v * v; }
    float mu = s * (1.f / CC);
    smu[px] = mu;
    srs[px] = rsqrtf(s2 * (1.f / CC) - mu * mu + 1e-5f);
  }
  __syncthreads();
  for (int i = threadIdx.x; i < CC * 64; i += 256) {
    int ci = i >> 6, px = i & 63;
    t[ci][px] = (t[ci][px] - smu[px]) * srs[px] * lnw[ci] + lnb[ci];
  }
  __syncthreads();
  int px = threadIdx.x & 63;
  int co0 = ((__builtin_amdgcn_readfirstlane((int)threadIdx.x)) >> 6) << 6;  // *64
  float acc[64];
#pragma unroll
  for (int j = 0; j < 64; j++) acc[j] = 0.f;
  for (int ci = 0; ci < CC; ci++) {
    float in = t[ci][px];
#pragma unroll
    for (int j = 0; j < 64; j++) acc[j] += p1w[(co0 + j) * CC + ci] * in;
  }
#pragma unroll
  for (int j = 0; j < 64; j++) {
    int co = co0 + j;
    y1[co * HWSZ + p0 + px] = acc[j] + p1b[co];
  }
}

// ---------------- K11: dw 3x3 (zero pad) + bias + relu + p2 + bias + residual
__global__ __launch_bounds__(256) void k_ffn2(const float* __restrict__ y1,
                                              const float* __restrict__ dww,
                                              const float* __restrict__ dwb,
                                              const float* __restrict__ p2w,
                                              const float* __restrict__ p2b,
                                              const float* __restrict__ x2,
                                              float* __restrict__ out, int bi) {
  __shared__ float ytile[64][100];  // 64 mid-ch x 10x10 (8x8 tile + halo)
  __shared__ float t[64][65];       // dw output [mid][px]
  int blk = blockIdx.x;
  int bx = blk & 31, by = blk >> 5;
  int r0 = by * 8 - 1, c0 = bx * 8 - 1;
  int px = threadIdx.x & 63;
  int co0 = ((__builtin_amdgcn_readfirstlane((int)threadIdx.x)) >> 6) << 5;
  float acc[32];
#pragma unroll
  for (int j = 0; j < 32; j++) acc[j] = 0.f;
  for (int m0 = 0; m0 < MIDC; m0 += 64) {
    __syncthreads();
    for (int i = threadIdx.x; i < 6400; i += 256) {
      int mc = i / 100, rc = i % 100;
      int rr = rc / 10, ccx = rc % 10;
      int gr = r0 + rr, gc = c0 + ccx;
      float v = 0.f;
      if (gr >= 0 && gr < HH && gc >= 0 && gc < WW)
        v = y1[(m0 + mc) * HWSZ + gr * WW + gc];
      ytile[mc][rc] = v;
    }
    __syncthreads();
    for (int i = threadIdx.x; i < 4096; i += 256) {
      int mc = i >> 6, pp = i & 63;
      int qy = pp >> 3, qx = pp & 7;
      const float* wp = dww + (m0 + mc) * 9;
      float s = dwb[m0 + mc];
#pragma unroll
      for (int dy = 0; dy < 3; dy++)
#pragma unroll
        for (int dx = 0; dx < 3; dx++)
          s += wp[dy * 3 + dx] * ytile[mc][(qy + dy) * 10 + qx + dx];
      t[mc][pp] = fmaxf(s, 0.f);
    }
    __syncthreads();
    for (int mc = 0; mc < 64; mc++) {
      float in = t[mc][px];
#pragma unroll
      for (int j = 0; j < 32; j++) acc[j] += p2w[(co0 + j) * MIDC + m0 + mc] * in;
    }
  }
  int gp = (by * 8 + (px >> 3)) * WW + bx * 8 + (px & 7);
#pragma unroll
  for (int j = 0; j < 32; j++) {
    int co = co0 + j;
    int gi = (bi * CC + co) * HWSZ + gp;
    out[gi] = x2[gi] + acc[j] + p2b[co];
  }
}

extern "C" void kernel_launch(void* const* d_in, const int* in_sizes, int n_in,
                              void* d_out, int out_size, void* d_ws, size_t ws_size,
                              hipStream_t stream) {
  const float* x    = (const float*)d_in[0];
  const float* illu = (const float*)d_in[1];
  const float* ln1w = (const float*)d_in[2];
  const float* ln1b = (const float*)d_in[3];
  const float* qw   = (const float*)d_in[4];
  const float* kw   = (const float*)d_in[5];
  const float* vw   = (const float*)d_in[6];
  const float* a1w  = (const float*)d_in[7];
  const float* a2w  = (const float*)d_in[8];
  const float* a2b  = (const float*)d_in[9];
  const float* tA   = (const float*)d_in[10];
  const float* tV   = (const float*)d_in[11];
  const float* pow_ = (const float*)d_in[12];
  const float* ln2w = (const float*)d_in[13];
  const float* ln2b = (const float*)d_in[14];
  const float* p1w  = (const float*)d_in[15];
  const float* p1b  = (const float*)d_in[16];
  const float* dww  = (const float*)d_in[17];
  const float* dwb  = (const float*)d_in[18];
  const float* p2w  = (const float*)d_in[19];
  const float* p2b  = (const float*)d_in[20];
  float* out = (float*)d_out;

  // workspace layout (floats); total need = 79,732,736 floats = 304.2 MiB
  float* ws   = (float*)d_ws;
  float* vbuf = ws;                       // 33,554,432  (v; later x2)
  float* r2   = ws + 33554432;
  float* qb   = r2;                       // 8,388,608
  float* kb   = qb + 8388608;             // 8,388,608
  float* a1b  = kb + 8388608;             // 8,388,608
  float* ab   = a1b + 8388608;            // 4,194,304
  float* outv = ab + 4194304;             // 16,777,216
  float* attnA = outv + 16777216;         // 4096
  float* attnK = attnA + 4096;            // 4096
  float* weff  = attnK + 4096;            // 32768
  float* y1 = r2;      // per-batch FFN mid buffer (16,777,216), reuses q/k space
  float* xn = out;     // d_out doubles as xn scratch (dead before final write)

  k_ln1<<<1024, 256, 0, stream>>>(x, ln1w, ln1b, xn);
  k_dws2<<<32768, 256, 0, stream>>>(xn, qw, qb);
  k_dws2<<<32768, 256, 0, stream>>>(xn, a1w, a1b);
  k_kconv<<<1024, 256, 0, stream>>>(xn, kw, kb);
  k_v1x1<<<4096, 256, 0, stream>>>(xn, vw, illu, vbuf);
  k_a2<<<1024, 256, 0, stream>>>(a1b, a2w, a2b, ab);
  k_attn<<<32, 256, 0, stream>>>(qb, kb, ab, tA, tV, attnA, attnK);
  k_weff<<<4, 256, 0, stream>>>(pow_, attnA, weff);
  k_outv<<<1024, 256, 0, stream>>>(attnK, vbuf, outv);
  k_x2<<<4096, 256, 0, stream>>>(x, weff, outv, vbuf);
  for (int bi = 0; bi < 4; bi++) {
    k_ln2p1<<<1024, 256, 0, stream>>>(vbuf, ln2w, ln2b, p1w, p1b, y1, bi);
    k_ffn2<<<1024, 256, 0, stream>>>(y1, dww, dwb, p2w, p2b, vbuf, out, bi);
  }
}

// Round 2
// 7325.050 us; speedup vs baseline: 1.6746x; 1.6746x over previous
//
#include <hip/hip_runtime.h>

#define BB 4
#define CC 128
#define HH 256
#define WW 256
#define HWSZ 65536
#define H2 128
#define W2 128
#define L4SZ 16384
#define MIDC 256
#define NHEADS 8

// ---------------- K1: LayerNorm over channel dim (NCHW), one thread per pixel
__global__ __launch_bounds__(256) void k_ln1(const float* __restrict__ x,
                                             const float* __restrict__ w,
                                             const float* __restrict__ b,
                                             float* __restrict__ out) {
  int idx = blockIdx.x * 256 + threadIdx.x;  // B*HW threads
  int bi = idx >> 16;
  int p  = idx & 65535;
  const float* xp = x + (bi * CC) * HWSZ + p;
  float s = 0.f, s2 = 0.f;
  for (int c = 0; c < CC; c++) { float v = xp[c * HWSZ]; s += v; s2 += v * v; }
  float mu  = s * (1.f / CC);
  float rstd = rsqrtf(s2 * (1.f / CC) - mu * mu + 1e-5f);
  float* op = out + (bi * CC) * HWSZ + p;
  for (int c = 0; c < CC; c++)
    op[c * HWSZ] = (xp[c * HWSZ] - mu) * rstd * w[c] + b[c];
}

// ---------------- K2: depthwise 3x3 stride-2 conv, reflect pad 1 (q and a1)
__global__ __launch_bounds__(256) void k_dws2(const float* __restrict__ in,
                                              const float* __restrict__ w,
                                              float* __restrict__ out) {
  int idx = blockIdx.x * 256 + threadIdx.x;  // B*C*L4
  int xo = idx & (W2 - 1);
  int t = idx >> 7;
  int yo = t & (H2 - 1); t >>= 7;
  int c = t & (CC - 1);
  int bi = t >> 7;
  const float* ip = in + (bi * CC + c) * HWSZ;
  const float* wp = w + c * 9;
  float acc = 0.f;
#pragma unroll
  for (int dy = 0; dy < 3; dy++) {
    int r = 2 * yo + dy - 1; r = r < 0 ? -r : r;  // reflect(-1)=1; max 255
#pragma unroll
    for (int dx = 0; dx < 3; dx++) {
      int cc2 = 2 * xo + dx - 1; cc2 = cc2 < 0 ? -cc2 : cc2;
      acc += wp[dy * 3 + dx] * ip[r * WW + cc2];
    }
  }
  out[idx] = acc;
}

// ---------------- K3: dense 3x3 stride-2 conv 128->128, reflect pad (k)
// block = 256 thr, computes 8x8 output pixels x all 128 co; ci chunked by 8
__global__ __launch_bounds__(256) void k_kconv(const float* __restrict__ xn,
                                               const float* __restrict__ kw,
                                               float* __restrict__ outk) {
  __shared__ float tile[8][289];        // 8 ci x 17x17
  __shared__ float wlds[128][8][9];     // all co x 8 ci x 9 taps
  int blk = blockIdx.x;
  int bx = blk & 15;
  int by = (blk >> 4) & 15;
  int bi = blk >> 8;
  int r0 = by * 16 - 1, c0 = bx * 16 - 1;
  int px = threadIdx.x & 63;
  int co0 = ((__builtin_amdgcn_readfirstlane((int)threadIdx.x)) >> 6) << 5;
  int py = px >> 3, pxx = px & 7;
  float acc[32];
#pragma unroll
  for (int j = 0; j < 32; j++) acc[j] = 0.f;
  for (int ci0 = 0; ci0 < CC; ci0 += 8) {
    __syncthreads();
    for (int i = threadIdx.x; i < 8 * 289; i += 256) {
      int ci = i / 289, rc = i % 289;
      int rr = rc / 17, ccx = rc % 17;
      int gr = r0 + rr; gr = gr < 0 ? -gr : gr;
      int gc = c0 + ccx; gc = gc < 0 ? -gc : gc;
      tile[ci][rc] = xn[(bi * CC + ci0 + ci) * HWSZ + gr * WW + gc];
    }
    for (int i = threadIdx.x; i < 128 * 8 * 9; i += 256) {
      int co = i / 72, r = i % 72, ci = r / 9, tt = r % 9;
      wlds[co][ci][tt] = kw[(co * CC + ci0 + ci) * 9 + tt];
    }
    __syncthreads();
#pragma unroll
    for (int ci = 0; ci < 8; ci++) {
      int base = 2 * py * 17 + 2 * pxx;
      float v0 = tile[ci][base],      v1 = tile[ci][base + 1],  v2 = tile[ci][base + 2];
      float v3 = tile[ci][base + 17], v4 = tile[ci][base + 18], v5 = tile[ci][base + 19];
      float v6 = tile[ci][base + 34], v7 = tile[ci][base + 35], v8 = tile[ci][base + 36];
#pragma unroll
      for (int j = 0; j < 32; j++) {
        const float* wp = &wlds[co0 + j][ci][0];
        acc[j] += wp[0] * v0 + wp[1] * v1 + wp[2] * v2 + wp[3] * v3 + wp[4] * v4 +
                  wp[5] * v5 + wp[6] * v6 + wp[7] * v7 + wp[8] * v8;
      }
    }
  }
  int oy = by * 8 + py, ox = bx * 8 + pxx;
#pragma unroll
  for (int j = 0; j < 32; j++)
    outk[(bi * CC + co0 + j) * L4SZ + oy * W2 + ox] = acc[j];
}

// ---------------- K4: 1x1 conv 128->128 then * illu (v)
__global__ __launch_bounds__(256) void k_v1x1(const float* __restrict__ xn,
                                              const float* __restrict__ vw,
                                              const float* __restrict__ illu,
                                              float* __restrict__ v) {
  __shared__ float t[CC][64];
  int blk = blockIdx.x;
  int bi = blk >> 10;            // HW/64 = 1024 blocks per batch
  int p0 = (blk & 1023) * 64;
  for (int i = threadIdx.x; i < CC * 64; i += 256) {
    int ci = i >> 6, px = i & 63;
    t[ci][px] = xn[(bi * CC + ci) * HWSZ + p0 + px];
  }
  __syncthreads();
  int px = threadIdx.x & 63;
  int co0 = ((__builtin_amdgcn_readfirstlane((int)threadIdx.x)) >> 6) << 5;
  float acc[32];
#pragma unroll
  for (int j = 0; j < 32; j++) acc[j] = 0.f;
  for (int ci = 0; ci < CC; ci++) {
    float in = t[ci][px];
#pragma unroll
    for (int j = 0; j < 32; j++) acc[j] += vw[(co0 + j) * CC + ci] * in;
  }
#pragma unroll
  for (int j = 0; j < 32; j++) {
    int gi = (bi * CC + co0 + j) * HWSZ + p0 + px;
    v[gi] = acc[j] * illu[gi];
  }
}

// ---------------- K5: 1x1 conv 128->64 + bias (a2)
__global__ __launch_bounds__(256) void k_a2(const float* __restrict__ a1,
                                            const float* __restrict__ w,
                                            const float* __restrict__ bias,
                                            float* __restrict__ ab) {
  __shared__ float t[CC][64];
  int blk = blockIdx.x;
  int bi = blk >> 8;             // L4/64 = 256 blocks per batch
  int p0 = (blk & 255) * 64;
  for (int i = threadIdx.x; i < CC * 64; i += 256) {
    int ci = i >> 6, px = i & 63;
    t[ci][px] = a1[(bi * CC + ci) * L4SZ + p0 + px];
  }
  __syncthreads();
  int px = threadIdx.x & 63;
  int co0 = ((__builtin_amdgcn_readfirstlane((int)threadIdx.x)) >> 6) << 4;  // *16
  float acc[16];
#pragma unroll
  for (int j = 0; j < 16; j++) acc[j] = 0.f;
  for (int ci = 0; ci < CC; ci++) {
    float in = t[ci][px];
#pragma unroll
    for (int j = 0; j < 16; j++) acc[j] += w[(co0 + j) * CC + ci] * in;
  }
#pragma unroll
  for (int j = 0; j < 16; j++)
    ab[(bi * 64 + co0 + j) * L4SZ + p0 + px] = acc[j] + bias[co0 + j];
}

// ---------------- K6a: all 296 dot products per (b,h), one block per dot
// d<128: q[c].a[e]  (c=d>>3,e=d&7); d<256: a[e].k[c]; 256..271: |q|^2; 272..279: |a|^2; 280..295: |k|^2
__global__ __launch_bounds__(256) void k_dots(const float* __restrict__ q,
                                              const float* __restrict__ k,
                                              const float* __restrict__ a,
                                              float* __restrict__ dots) {
  int blk = blockIdx.x;           // 32 * 296
  int bh = blk / 296, d = blk % 296;
  int bi = bh >> 3, h = bh & 7;
  const float* qb = q + (bi * CC + h * 16) * L4SZ;
  const float* kb = k + (bi * CC + h * 16) * L4SZ;
  const float* ab = a + (bi * 64 + h * 8) * L4SZ;
  const float *ra, *rb;
  if (d < 128)      { ra = qb + (d >> 3) * L4SZ; rb = ab + (d & 7) * L4SZ; }
  else if (d < 256) { int dd = d - 128; ra = ab + (dd >> 4) * L4SZ; rb = kb + (dd & 15) * L4SZ; }
  else if (d < 272) { ra = qb + (d - 256) * L4SZ; rb = ra; }
  else if (d < 280) { ra = ab + (d - 272) * L4SZ; rb = ra; }
  else              { ra = kb + (d - 280) * L4SZ; rb = ra; }
  const float4* ra4 = (const float4*)ra;
  const float4* rb4 = (const float4*)rb;
  float s = 0.f;
#pragma unroll 4
  for (int l = threadIdx.x; l < L4SZ / 4; l += 256) {
    float4 va = ra4[l], vb = rb4[l];
    s += va.x * vb.x + va.y * vb.y + va.z * vb.z + va.w * vb.w;
  }
#pragma unroll
  for (int off = 32; off > 0; off >>= 1) s += __shfl_down(s, off);
  __shared__ float ws4[4];
  if ((threadIdx.x & 63) == 0) ws4[threadIdx.x >> 6] = s;
  __syncthreads();
  if (threadIdx.x == 0) dots[bh * 296 + d] = ws4[0] + ws4[1] + ws4[2] + ws4[3];
}

// ---------------- K6b: softmax over the dots table (tiny)
__global__ __launch_bounds__(64) void k_softmax(const float* __restrict__ dots,
                                                const float* __restrict__ tA,
                                                const float* __restrict__ tV,
                                                float* __restrict__ attnA,
                                                float* __restrict__ attnK) {
  int bh = blockIdx.x;            // 32
  int h = bh & 7;
  const float* dt = dots + bh * 296;
  float ta = tA[h], tv = tV[h];
  if (threadIdx.x < 16) {
    int c = threadIdx.x;
    float nq = fmaxf(sqrtf(dt[256 + c]), 1e-12f);
    float lg[8]; float m = -1e30f;
#pragma unroll
    for (int e = 0; e < 8; e++) {
      float na = fmaxf(sqrtf(dt[272 + e]), 1e-12f);
      lg[e] = dt[c * 8 + e] / (nq * na) * ta;
      m = fmaxf(m, lg[e]);
    }
    float sum = 0.f;
#pragma unroll
    for (int e = 0; e < 8; e++) { lg[e] = expf(lg[e] - m); sum += lg[e]; }
    float inv = 1.f / sum;
#pragma unroll
    for (int e = 0; e < 8; e++) attnA[(bh * 16 + c) * 8 + e] = lg[e] * inv;
  } else if (threadIdx.x < 24) {
    int e = threadIdx.x - 16;
    float na = fmaxf(sqrtf(dt[272 + e]), 1e-12f);
    float lg[16]; float m = -1e30f;
#pragma unroll
    for (int c = 0; c < 16; c++) {
      float nk = fmaxf(sqrtf(dt[280 + c]), 1e-12f);
      lg[c] = dt[128 + e * 16 + c] / (na * nk) * tv;
      m = fmaxf(m, lg[c]);
    }
    float sum = 0.f;
#pragma unroll
    for (int c = 0; c < 16; c++) { lg[c] = expf(lg[c] - m); sum += lg[c]; }
    float inv = 1.f / sum;
#pragma unroll
    for (int c = 0; c < 16; c++) attnK[(bh * 8 + e) * 16 + c] = lg[c] * inv;
  }
}

// ---------------- K7: W_eff[b][co][h*8+d] = sum_c po[co][h*16+c]*attnA[b,h,c,d]
__global__ __launch_bounds__(256) void k_weff(const float* __restrict__ po,
                                              const float* __restrict__ attnA,
                                              float* __restrict__ weff) {
  int bi = blockIdx.x;
  for (int o = threadIdx.x; o < 128 * 64; o += 256) {
    int co = o >> 6, hd = o & 63, h = hd >> 3, d = hd & 7;
    float s = 0.f;
#pragma unroll
    for (int c = 0; c < 16; c++)
      s += po[co * CC + h * 16 + c] * attnA[((bi * 8 + h) * 16 + c) * 8 + d];
    weff[bi * 8192 + o] = s;
  }
}

// ---------------- K8: out_v[b,hd,m] = sum_c attnK[b,h,d,c]*v[b,h*16+c,m]
__global__ __launch_bounds__(256) void k_outv(const float* __restrict__ attnK,
                                              const float* __restrict__ v,
                                              float* __restrict__ outv) {
  __shared__ float ak[8][8][16];
  int idx = blockIdx.x * 256 + threadIdx.x;  // B*HW
  int bi = idx >> 16;
  int m  = idx & 65535;
  for (int i = threadIdx.x; i < 1024; i += 256)
    ((float*)ak)[i] = attnK[bi * 1024 + i];
  __syncthreads();
  float acc[64];
#pragma unroll
  for (int j = 0; j < 64; j++) acc[j] = 0.f;
  const float* vb = v + bi * CC * HWSZ + m;
#pragma unroll
  for (int h = 0; h < 8; h++)
#pragma unroll
    for (int c = 0; c < 16; c++) {
      float vv = vb[(h * 16 + c) * HWSZ];
#pragma unroll
      for (int d = 0; d < 8; d++) acc[h * 8 + d] += ak[h][d][c] * vv;
    }
  float* ob = outv + bi * 64 * HWSZ + m;
#pragma unroll
  for (int hd = 0; hd < 64; hd++) ob[hd * HWSZ] = acc[hd];
}

// ---------------- K9: x2 = x + W_eff @ out_v   (GEMM M=128,K=64 per b)
__global__ __launch_bounds__(256) void k_x2(const float* __restrict__ x,
                                            const float* __restrict__ weff,
                                            const float* __restrict__ outv,
                                            float* __restrict__ x2) {
  __shared__ float t[64][64];
  __shared__ float wsm[128][64];
  int blk = blockIdx.x;
  int bi = blk >> 10;
  int p0 = (blk & 1023) * 64;
  for (int i = threadIdx.x; i < 4096; i += 256) {
    int hd = i >> 6, px = i & 63;
    t[hd][px] = outv[(bi * 64 + hd) * HWSZ + p0 + px];
  }
  for (int i = threadIdx.x; i < 8192; i += 256)
    ((float*)wsm)[i] = weff[bi * 8192 + i];
  __syncthreads();
  int px = threadIdx.x & 63;
  int co0 = ((__builtin_amdgcn_readfirstlane((int)threadIdx.x)) >> 6) << 5;
  float acc[32];
#pragma unroll
  for (int j = 0; j < 32; j++) acc[j] = 0.f;
  for (int kk = 0; kk < 64; kk++) {
    float ov = t[kk][px];
#pragma unroll
    for (int j = 0; j < 32; j++) acc[j] += wsm[co0 + j][kk] * ov;
  }
#pragma unroll
  for (int j = 0; j < 32; j++) {
    int gi = (bi * CC + co0 + j) * HWSZ + p0 + px;
    x2[gi] = x[gi] + acc[j];
  }
}

// ---------------- K10: LN2 + p1 (1x1 conv 128->256 + bias), per batch
__global__ __launch_bounds__(256) void k_ln2p1(const float* __restrict__ x2,
                                               const float* __restrict__ lnw,
                                               const float* __restrict__ lnb,
                                               const float* __restrict__ p1w,
                                               const float* __restrict__ p1b,
                                               float* __restrict__ y1, int bi) {
  __shared__ float t[CC][64];
  __shared__ float smu[64], srs[64];
  int p0 = blockIdx.x * 64;
  for (int i = threadIdx.x; i < CC * 64; i += 256) {
    int ci = i >> 6, px = i & 63;
    t[ci][px] = x2[(bi * CC + ci) * HWSZ + p0 + px];
  }
  __syncthreads();
  if (threadIdx.x < 64) {
    int px = threadIdx.x;
    float s = 0.f, s2 = 0.f;
    for (int ci = 0; ci < CC; ci++) { float v = t[ci][px]; s += v; s2 += v * v; }
    float mu = s * (1.f / CC);
    smu[px] = mu;
    srs[px] = rsqrtf(s2 * (1.f / CC) - mu * mu + 1e-5f);
  }
  __syncthreads();
  for (int i = threadIdx.x; i < CC * 64; i += 256) {
    int ci = i >> 6, px = i & 63;
    t[ci][px] = (t[ci][px] - smu[px]) * srs[px] * lnw[ci] + lnb[ci];
  }
  __syncthreads();
  int px = threadIdx.x & 63;
  int co0 = ((__builtin_amdgcn_readfirstlane((int)threadIdx.x)) >> 6) << 6;  // *64
  float acc[64];
#pragma unroll
  for (int j = 0; j < 64; j++) acc[j] = 0.f;
  for (int ci = 0; ci < CC; ci++) {
    float in = t[ci][px];
#pragma unroll
    for (int j = 0; j < 64; j++) acc[j] += p1w[(co0 + j) * CC + ci] * in;
  }
#pragma unroll
  for (int j = 0; j < 64; j++) {
    int co = co0 + j;
    y1[co * HWSZ + p0 + px] = acc[j] + p1b[co];
  }
}

// ---------------- K11: dw 3x3 (zero pad) + bias + relu + p2 + bias + residual
__global__ __launch_bounds__(256) void k_ffn2(const float* __restrict__ y1,
                                              const float* __restrict__ dww,
                                              const float* __restrict__ dwb,
                                              const float* __restrict__ p2w,
                                              const float* __restrict__ p2b,
                                              const float* __restrict__ x2,
                                              float* __restrict__ out, int bi) {
  __shared__ float ytile[64][100];  // 64 mid-ch x 10x10 (8x8 tile + halo)
  __shared__ float t[64][65];       // dw output [mid][px]
  int blk = blockIdx.x;
  int bx = blk & 31, by = blk >> 5;
  int r0 = by * 8 - 1, c0 = bx * 8 - 1;
  int px = threadIdx.x & 63;
  int co0 = ((__builtin_amdgcn_readfirstlane((int)threadIdx.x)) >> 6) << 5;
  float acc[32];
#pragma unroll
  for (int j = 0; j < 32; j++) acc[j] = 0.f;
  for (int m0 = 0; m0 < MIDC; m0 += 64) {
    __syncthreads();
    for (int i = threadIdx.x; i < 6400; i += 256) {
      int mc = i / 100, rc = i % 100;
      int rr = rc / 10, ccx = rc % 10;
      int gr = r0 + rr, gc = c0 + ccx;
      float v = 0.f;
      if (gr >= 0 && gr < HH && gc >= 0 && gc < WW)
        v = y1[(m0 + mc) * HWSZ + gr * WW + gc];
      ytile[mc][rc] = v;
    }
    __syncthreads();
    for (int i = threadIdx.x; i < 4096; i += 256) {
      int mc = i >> 6, pp = i & 63;
      int qy = pp >> 3, qx = pp & 7;
      const float* wp = dww + (m0 + mc) * 9;
      float s = dwb[m0 + mc];
#pragma unroll
      for (int dy = 0; dy < 3; dy++)
#pragma unroll
        for (int dx = 0; dx < 3; dx++)
          s += wp[dy * 3 + dx] * ytile[mc][(qy + dy) * 10 + qx + dx];
      t[mc][pp] = fmaxf(s, 0.f);
    }
    __syncthreads();
    for (int mc = 0; mc < 64; mc++) {
      float in = t[mc][px];
#pragma unroll
      for (int j = 0; j < 32; j++) acc[j] += p2w[(co0 + j) * MIDC + m0 + mc] * in;
    }
  }
  int gp = (by * 8 + (px >> 3)) * WW + bx * 8 + (px & 7);
#pragma unroll
  for (int j = 0; j < 32; j++) {
    int co = co0 + j;
    int gi = (bi * CC + co) * HWSZ + gp;
    out[gi] = x2[gi] + acc[j] + p2b[co];
  }
}

extern "C" void kernel_launch(void* const* d_in, const int* in_sizes, int n_in,
                              void* d_out, int out_size, void* d_ws, size_t ws_size,
                              hipStream_t stream) {
  const float* x    = (const float*)d_in[0];
  const float* illu = (const float*)d_in[1];
  const float* ln1w = (const float*)d_in[2];
  const float* ln1b = (const float*)d_in[3];
  const float* qw   = (const float*)d_in[4];
  const float* kw   = (const float*)d_in[5];
  const float* vw   = (const float*)d_in[6];
  const float* a1w  = (const float*)d_in[7];
  const float* a2w  = (const float*)d_in[8];
  const float* a2b  = (const float*)d_in[9];
  const float* tA   = (const float*)d_in[10];
  const float* tV   = (const float*)d_in[11];
  const float* pow_ = (const float*)d_in[12];
  const float* ln2w = (const float*)d_in[13];
  const float* ln2b = (const float*)d_in[14];
  const float* p1w  = (const float*)d_in[15];
  const float* p1b  = (const float*)d_in[16];
  const float* dww  = (const float*)d_in[17];
  const float* dwb  = (const float*)d_in[18];
  const float* p2w  = (const float*)d_in[19];
  const float* p2b  = (const float*)d_in[20];
  float* out = (float*)d_out;

  // workspace layout (floats)
  float* ws   = (float*)d_ws;
  float* vbuf = ws;                       // 33,554,432  (v; later x2)
  float* r2   = ws + 33554432;
  float* qb   = r2;                       // 8,388,608
  float* kb   = qb + 8388608;             // 8,388,608
  float* a1b  = kb + 8388608;             // 8,388,608
  float* ab   = a1b + 8388608;            // 4,194,304
  float* outv = ab + 4194304;             // 16,777,216
  float* attnA = outv + 16777216;         // 4096
  float* attnK = attnA + 4096;            // 4096
  float* weff  = attnK + 4096;            // 32768
  float* dots  = weff + 32768;            // 32*296 = 9472
  float* y1 = r2;      // per-batch FFN mid buffer (16,777,216), reuses q/k space
  float* xn = out;     // d_out doubles as xn scratch (dead before final write)

  k_ln1<<<1024, 256, 0, stream>>>(x, ln1w, ln1b, xn);
  k_dws2<<<32768, 256, 0, stream>>>(xn, qw, qb);
  k_dws2<<<32768, 256, 0, stream>>>(xn, a1w, a1b);
  k_kconv<<<1024, 256, 0, stream>>>(xn, kw, kb);
  k_v1x1<<<4096, 256, 0, stream>>>(xn, vw, illu, vbuf);
  k_a2<<<1024, 256, 0, stream>>>(a1b, a2w, a2b, ab);
  k_dots<<<32 * 296, 256, 0, stream>>>(qb, kb, ab, dots);
  k_softmax<<<32, 64, 0, stream>>>(dots, tA, tV, attnA, attnK);
  k_weff<<<4, 256, 0, stream>>>(pow_, attnA, weff);
  k_outv<<<1024, 256, 0, stream>>>(attnK, vbuf, outv);
  k_x2<<<4096, 256, 0, stream>>>(x, weff, outv, vbuf);
  for (int bi = 0; bi < 4; bi++) {
    k_ln2p1<<<1024, 256, 0, stream>>>(vbuf, ln2w, ln2b, p1w, p1b, y1, bi);
    k_ffn2<<<1024, 256, 0, stream>>>(y1, dww, dwb, p2w, p2b, vbuf, out, bi);
  }
}

// Round 3
// 3298.999 us; speedup vs baseline: 3.7183x; 2.2204x over previous
//
#include <hip/hip_runtime.h>

#define BB 4
#define CC 128
#define HH 256
#define WW 256
#define HWSZ 65536
#define H2 128
#define W2 128
#define L4SZ 16384
#define MIDC 256
#define NHEADS 8

typedef __attribute__((ext_vector_type(8))) short short8;
typedef __attribute__((ext_vector_type(4))) float f32x4;

__device__ __forceinline__ short f2bf(float v) {
  unsigned u = __builtin_bit_cast(unsigned, v);
  u += 0x7fffu + ((u >> 16) & 1u);
  return (short)(u >> 16);
}

// ---------------- K1: LayerNorm over channel dim; emits f32 NCHW + bf16 NHWC
__global__ __launch_bounds__(256) void k_ln1(const float* __restrict__ x,
                                             const float* __restrict__ w,
                                             const float* __restrict__ b,
                                             float* __restrict__ out,
                                             short* __restrict__ xnt) {
  int idx = blockIdx.x * 256 + threadIdx.x;  // B*HW threads
  int bi = idx >> 16;
  int p  = idx & 65535;
  const float* xp = x + (bi * CC) * HWSZ + p;
  float s = 0.f, s2 = 0.f;
  for (int c = 0; c < CC; c++) { float v = xp[c * HWSZ]; s += v; s2 += v * v; }
  float mu  = s * (1.f / CC);
  float rstd = rsqrtf(s2 * (1.f / CC) - mu * mu + 1e-5f);
  float* op = out + (bi * CC) * HWSZ + p;
  short* tp = xnt + (size_t)idx * CC;      // NHWC row for this pixel
  for (int c0 = 0; c0 < CC; c0 += 8) {
    short8 pk;
#pragma unroll
    for (int j = 0; j < 8; j++) {
      float v = (xp[(c0 + j) * HWSZ] - mu) * rstd * w[c0 + j] + b[c0 + j];
      op[(c0 + j) * HWSZ] = v;
      pk[j] = f2bf(v);
    }
    *(short8*)(tp + c0) = pk;
  }
}

// ---------------- weight cast: wt[tap][co][ci] bf16 from kw[co][ci][tap] f32
__global__ __launch_bounds__(256) void k_wcast(const float* __restrict__ kw,
                                               short* __restrict__ wt) {
  int idx = blockIdx.x * 256 + threadIdx.x;  // 9*128*128
  if (idx >= 9 * 128 * 128) return;
  int ci = idx & 127, co = (idx >> 7) & 127, tap = idx >> 14;
  wt[idx] = f2bf(kw[(co * CC + ci) * 9 + tap]);
}

// ---------------- K2: depthwise 3x3 stride-2 conv, reflect pad 1 (q and a1)
__global__ __launch_bounds__(256) void k_dws2(const float* __restrict__ in,
                                              const float* __restrict__ w,
                                              float* __restrict__ out) {
  int idx = blockIdx.x * 256 + threadIdx.x;  // B*C*L4
  int xo = idx & (W2 - 1);
  int t = idx >> 7;
  int yo = t & (H2 - 1); t >>= 7;
  int c = t & (CC - 1);
  int bi = t >> 7;
  const float* ip = in + (bi * CC + c) * HWSZ;
  const float* wp = w + c * 9;
  float acc = 0.f;
#pragma unroll
  for (int dy = 0; dy < 3; dy++) {
    int r = 2 * yo + dy - 1; r = r < 0 ? -r : r;  // reflect(-1)=1; max 255
#pragma unroll
    for (int dx = 0; dx < 3; dx++) {
      int cc2 = 2 * xo + dx - 1; cc2 = cc2 < 0 ? -cc2 : cc2;
      acc += wp[dy * 3 + dx] * ip[r * WW + cc2];
    }
  }
  out[idx] = acc;
}

// ---------------- K3: dense 3x3 s2 conv 128->128 via MFMA (implicit GEMM)
// block: 128 co x 64 px (8x8 tile), 4 waves, K = ci(32-chunks) x 9 taps
__global__ __launch_bounds__(256) void k_kconv_mfma(const short* __restrict__ xnt,
                                                    const short* __restrict__ wt,
                                                    float* __restrict__ outk) {
  __shared__ short8 ldsb[1156];  // 289 pixels x 4 granules(8ci) , granule-swizzled
  int blk = blockIdx.x;
  int bx = blk & 15, by = (blk >> 4) & 15, bi = blk >> 8;
  int r0 = by * 16 - 1, c0 = bx * 16 - 1;
  int lane = threadIdx.x & 63, wv = threadIdx.x >> 6;
  int px0 = wv * 16;
  int pxl = px0 + (lane & 15);
  int py = pxl >> 3, pxx = pxl & 7;
  int g = lane >> 4;
  f32x4 acc[8];
#pragma unroll
  for (int m = 0; m < 8; m++) acc[m] = (f32x4){0.f, 0.f, 0.f, 0.f};
  for (int ci0 = 0; ci0 < CC; ci0 += 32) {
    __syncthreads();
    for (int i = threadIdx.x; i < 1156; i += 256) {
      int p = i >> 2, gg = i & 3;
      int rr = p / 17, cc = p - rr * 17;
      int gr = r0 + rr; gr = gr < 0 ? -gr : gr;
      int gc = c0 + cc; gc = gc < 0 ? -gc : gc;
      int slot = gg ^ ((p >> 1) & 3);
      ldsb[p * 4 + slot] =
          *(const short8*)(xnt + (size_t)((bi * HWSZ + gr * WW + gc) * CC + ci0 + gg * 8));
    }
    __syncthreads();
#pragma unroll
    for (int tap = 0; tap < 9; tap++) {
      int dy = tap / 3, dx = tap - dy * 3;
      int p = (2 * py + dy) * 17 + 2 * pxx + dx;
      int slot = g ^ ((p >> 1) & 3);
      short8 bfrag = ldsb[p * 4 + slot];
      const short* wbase = wt + (tap * 128 + (lane & 15)) * 128 + ci0 + g * 8;
#pragma unroll
      for (int m = 0; m < 8; m++) {
        short8 afrag = *(const short8*)(wbase + m * 16 * 128);
        acc[m] = __builtin_amdgcn_mfma_f32_16x16x32_bf16(afrag, bfrag, acc[m], 0, 0, 0);
      }
    }
  }
  int oy = by * 8 + py, ox = bx * 8 + pxx;
  int rb = g * 4;
#pragma unroll
  for (int m = 0; m < 8; m++)
#pragma unroll
    for (int r = 0; r < 4; r++)
      outk[(bi * CC + m * 16 + rb + r) * L4SZ + oy * W2 + ox] = acc[m][r];
}

// ---------------- K4: 1x1 conv 128->128 then * illu (v)
__global__ __launch_bounds__(256) void k_v1x1(const float* __restrict__ xn,
                                              const float* __restrict__ vw,
                                              const float* __restrict__ illu,
                                              float* __restrict__ v) {
  __shared__ float t[CC][64];
  int blk = blockIdx.x;
  int bi = blk >> 10;            // HW/64 = 1024 blocks per batch
  int p0 = (blk & 1023) * 64;
  for (int i = threadIdx.x; i < CC * 64; i += 256) {
    int ci = i >> 6, px = i & 63;
    t[ci][px] = xn[(bi * CC + ci) * HWSZ + p0 + px];
  }
  __syncthreads();
  int px = threadIdx.x & 63;
  int co0 = ((__builtin_amdgcn_readfirstlane((int)threadIdx.x)) >> 6) << 5;
  float acc[32];
#pragma unroll
  for (int j = 0; j < 32; j++) acc[j] = 0.f;
  for (int ci = 0; ci < CC; ci++) {
    float in = t[ci][px];
#pragma unroll
    for (int j = 0; j < 32; j++) acc[j] += vw[(co0 + j) * CC + ci] * in;
  }
#pragma unroll
  for (int j = 0; j < 32; j++) {
    int gi = (bi * CC + co0 + j) * HWSZ + p0 + px;
    v[gi] = acc[j] * illu[gi];
  }
}

// ---------------- K5: 1x1 conv 128->64 + bias (a2)
__global__ __launch_bounds__(256) void k_a2(const float* __restrict__ a1,
                                            const float* __restrict__ w,
                                            const float* __restrict__ bias,
                                            float* __restrict__ ab) {
  __shared__ float t[CC][64];
  int blk = blockIdx.x;
  int bi = blk >> 8;             // L4/64 = 256 blocks per batch
  int p0 = (blk & 255) * 64;
  for (int i = threadIdx.x; i < CC * 64; i += 256) {
    int ci = i >> 6, px = i & 63;
    t[ci][px] = a1[(bi * CC + ci) * L4SZ + p0 + px];
  }
  __syncthreads();
  int px = threadIdx.x & 63;
  int co0 = ((__builtin_amdgcn_readfirstlane((int)threadIdx.x)) >> 6) << 4;  // *16
  float acc[16];
#pragma unroll
  for (int j = 0; j < 16; j++) acc[j] = 0.f;
  for (int ci = 0; ci < CC; ci++) {
    float in = t[ci][px];
#pragma unroll
    for (int j = 0; j < 16; j++) acc[j] += w[(co0 + j) * CC + ci] * in;
  }
#pragma unroll
  for (int j = 0; j < 16; j++)
    ab[(bi * 64 + co0 + j) * L4SZ + p0 + px] = acc[j] + bias[co0 + j];
}

// ---------------- K6a: all 296 dot products per (b,h), one block per dot
__global__ __launch_bounds__(256) void k_dots(const float* __restrict__ q,
                                              const float* __restrict__ k,
                                              const float* __restrict__ a,
                                              float* __restrict__ dots) {
  int blk = blockIdx.x;           // 32 * 296
  int bh = blk / 296, d = blk % 296;
  int bi = bh >> 3, h = bh & 7;
  const float* qb = q + (bi * CC + h * 16) * L4SZ;
  const float* kb = k + (bi * CC + h * 16) * L4SZ;
  const float* ab = a + (bi * 64 + h * 8) * L4SZ;
  const float *ra, *rb;
  if (d < 128)      { ra = qb + (d >> 3) * L4SZ; rb = ab + (d & 7) * L4SZ; }
  else if (d < 256) { int dd = d - 128; ra = ab + (dd >> 4) * L4SZ; rb = kb + (dd & 15) * L4SZ; }
  else if (d < 272) { ra = qb + (d - 256) * L4SZ; rb = ra; }
  else if (d < 280) { ra = ab + (d - 272) * L4SZ; rb = ra; }
  else              { ra = kb + (d - 280) * L4SZ; rb = ra; }
  const float4* ra4 = (const float4*)ra;
  const float4* rb4 = (const float4*)rb;
  float s = 0.f;
#pragma unroll 4
  for (int l = threadIdx.x; l < L4SZ / 4; l += 256) {
    float4 va = ra4[l], vb = rb4[l];
    s += va.x * vb.x + va.y * vb.y + va.z * vb.z + va.w * vb.w;
  }
#pragma unroll
  for (int off = 32; off > 0; off >>= 1) s += __shfl_down(s, off);
  __shared__ float ws4[4];
  if ((threadIdx.x & 63) == 0) ws4[threadIdx.x >> 6] = s;
  __syncthreads();
  if (threadIdx.x == 0) dots[bh * 296 + d] = ws4[0] + ws4[1] + ws4[2] + ws4[3];
}

// ---------------- K6b: softmax over the dots table (tiny)
__global__ __launch_bounds__(64) void k_softmax(const float* __restrict__ dots,
                                                const float* __restrict__ tA,
                                                const float* __restrict__ tV,
                                                float* __restrict__ attnA,
                                                float* __restrict__ attnK) {
  int bh = blockIdx.x;            // 32
  int h = bh & 7;
  const float* dt = dots + bh * 296;
  float ta = tA[h], tv = tV[h];
  if (threadIdx.x < 16) {
    int c = threadIdx.x;
    float nq = fmaxf(sqrtf(dt[256 + c]), 1e-12f);
    float lg[8]; float m = -1e30f;
#pragma unroll
    for (int e = 0; e < 8; e++) {
      float na = fmaxf(sqrtf(dt[272 + e]), 1e-12f);
      lg[e] = dt[c * 8 + e] / (nq * na) * ta;
      m = fmaxf(m, lg[e]);
    }
    float sum = 0.f;
#pragma unroll
    for (int e = 0; e < 8; e++) { lg[e] = expf(lg[e] - m); sum += lg[e]; }
    float inv = 1.f / sum;
#pragma unroll
    for (int e = 0; e < 8; e++) attnA[(bh * 16 + c) * 8 + e] = lg[e] * inv;
  } else if (threadIdx.x < 24) {
    int e = threadIdx.x - 16;
    float na = fmaxf(sqrtf(dt[272 + e]), 1e-12f);
    float lg[16]; float m = -1e30f;
#pragma unroll
    for (int c = 0; c < 16; c++) {
      float nk = fmaxf(sqrtf(dt[280 + c]), 1e-12f);
      lg[c] = dt[128 + e * 16 + c] / (na * nk) * tv;
      m = fmaxf(m, lg[c]);
    }
    float sum = 0.f;
#pragma unroll
    for (int c = 0; c < 16; c++) { lg[c] = expf(lg[c] - m); sum += lg[c]; }
    float inv = 1.f / sum;
#pragma unroll
    for (int c = 0; c < 16; c++) attnK[(bh * 8 + e) * 16 + c] = lg[c] * inv;
  }
}

// ---------------- K7: W_eff[b][co][h*8+d] = sum_c po[co][h*16+c]*attnA[b,h,c,d]
__global__ __launch_bounds__(256) void k_weff(const float* __restrict__ po,
                                              const float* __restrict__ attnA,
                                              float* __restrict__ weff) {
  int bi = blockIdx.x;
  for (int o = threadIdx.x; o < 128 * 64; o += 256) {
    int co = o >> 6, hd = o & 63, h = hd >> 3, d = hd & 7;
    float s = 0.f;
#pragma unroll
    for (int c = 0; c < 16; c++)
      s += po[co * CC + h * 16 + c] * attnA[((bi * 8 + h) * 16 + c) * 8 + d];
    weff[bi * 8192 + o] = s;
  }
}

// ---------------- K8: out_v[b,hd,m] = sum_c attnK[b,h,d,c]*v[b,h*16+c,m]
__global__ __launch_bounds__(256) void k_outv(const float* __restrict__ attnK,
                                              const float* __restrict__ v,
                                              float* __restrict__ outv) {
  __shared__ float ak[8][8][16];
  int idx = blockIdx.x * 256 + threadIdx.x;  // B*HW
  int bi = idx >> 16;
  int m  = idx & 65535;
  for (int i = threadIdx.x; i < 1024; i += 256)
    ((float*)ak)[i] = attnK[bi * 1024 + i];
  __syncthreads();
  float acc[64];
#pragma unroll
  for (int j = 0; j < 64; j++) acc[j] = 0.f;
  const float* vb = v + bi * CC * HWSZ + m;
#pragma unroll
  for (int h = 0; h < 8; h++)
#pragma unroll
    for (int c = 0; c < 16; c++) {
      float vv = vb[(h * 16 + c) * HWSZ];
#pragma unroll
      for (int d = 0; d < 8; d++) acc[h * 8 + d] += ak[h][d][c] * vv;
    }
  float* ob = outv + bi * 64 * HWSZ + m;
#pragma unroll
  for (int hd = 0; hd < 64; hd++) ob[hd * HWSZ] = acc[hd];
}

// ---------------- K9: x2 = x + W_eff @ out_v   (GEMM M=128,K=64 per b)
__global__ __launch_bounds__(256) void k_x2(const float* __restrict__ x,
                                            const float* __restrict__ weff,
                                            const float* __restrict__ outv,
                                            float* __restrict__ x2) {
  __shared__ float t[64][64];
  __shared__ float wsm[128][64];
  int blk = blockIdx.x;
  int bi = blk >> 10;
  int p0 = (blk & 1023) * 64;
  for (int i = threadIdx.x; i < 4096; i += 256) {
    int hd = i >> 6, px = i & 63;
    t[hd][px] = outv[(bi * 64 + hd) * HWSZ + p0 + px];
  }
  for (int i = threadIdx.x; i < 8192; i += 256)
    ((float*)wsm)[i] = weff[bi * 8192 + i];
  __syncthreads();
  int px = threadIdx.x & 63;
  int co0 = ((__builtin_amdgcn_readfirstlane((int)threadIdx.x)) >> 6) << 5;
  float acc[32];
#pragma unroll
  for (int j = 0; j < 32; j++) acc[j] = 0.f;
  for (int kk = 0; kk < 64; kk++) {
    float ov = t[kk][px];
#pragma unroll
    for (int j = 0; j < 32; j++) acc[j] += wsm[co0 + j][kk] * ov;
  }
#pragma unroll
  for (int j = 0; j < 32; j++) {
    int gi = (bi * CC + co0 + j) * HWSZ + p0 + px;
    x2[gi] = x[gi] + acc[j];
  }
}

// ---------------- K10: LN2 + p1 (1x1 conv 128->256 + bias), per batch
__global__ __launch_bounds__(256) void k_ln2p1(const float* __restrict__ x2,
                                               const float* __restrict__ lnw,
                                               const float* __restrict__ lnb,
                                               const float* __restrict__ p1w,
                                               const float* __restrict__ p1b,
                                               float* __restrict__ y1, int bi) {
  __shared__ float t[CC][64];
  __shared__ float smu[64], srs[64];
  int p0 = blockIdx.x * 64;
  for (int i = threadIdx.x; i < CC * 64; i += 256) {
    int ci = i >> 6, px = i & 63;
    t[ci][px] = x2[(bi * CC + ci) * HWSZ + p0 + px];
  }
  __syncthreads();
  if (threadIdx.x < 64) {
    int px = threadIdx.x;
    float s = 0.f, s2 = 0.f;
    for (int ci = 0; ci < CC; ci++) { float v = t[ci][px]; s += v; s2 += v * v; }
    float mu = s * (1.f / CC);
    smu[px] = mu;
    srs[px] = rsqrtf(s2 * (1.f / CC) - mu * mu + 1e-5f);
  }
  __syncthreads();
  for (int i = threadIdx.x; i < CC * 64; i += 256) {
    int ci = i >> 6, px = i & 63;
    t[ci][px] = (t[ci][px] - smu[px]) * srs[px] * lnw[ci] + lnb[ci];
  }
  __syncthreads();
  int px = threadIdx.x & 63;
  int co0 = ((__builtin_amdgcn_readfirstlane((int)threadIdx.x)) >> 6) << 6;  // *64
  float acc[64];
#pragma unroll
  for (int j = 0; j < 64; j++) acc[j] = 0.f;
  for (int ci = 0; ci < CC; ci++) {
    float in = t[ci][px];
#pragma unroll
    for (int j = 0; j < 64; j++) acc[j] += p1w[(co0 + j) * CC + ci] * in;
  }
#pragma unroll
  for (int j = 0; j < 64; j++) {
    int co = co0 + j;
    y1[co * HWSZ + p0 + px] = acc[j] + p1b[co];
  }
}

// ---------------- K11: dw 3x3 (zero pad) + bias + relu + p2 + bias + residual
__global__ __launch_bounds__(256) void k_ffn2(const float* __restrict__ y1,
                                              const float* __restrict__ dww,
                                              const float* __restrict__ dwb,
                                              const float* __restrict__ p2w,
                                              const float* __restrict__ p2b,
                                              const float* __restrict__ x2,
                                              float* __restrict__ out, int bi) {
  __shared__ float ytile[64][100];  // 64 mid-ch x 10x10 (8x8 tile + halo)
  __shared__ float t[64][65];       // dw output [mid][px]
  int blk = blockIdx.x;
  int bx = blk & 31, by = blk >> 5;
  int r0 = by * 8 - 1, c0 = bx * 8 - 1;
  int px = threadIdx.x & 63;
  int co0 = ((__builtin_amdgcn_readfirstlane((int)threadIdx.x)) >> 6) << 5;
  float acc[32];
#pragma unroll
  for (int j = 0; j < 32; j++) acc[j] = 0.f;
  for (int m0 = 0; m0 < MIDC; m0 += 64) {
    __syncthreads();
    for (int i = threadIdx.x; i < 6400; i += 256) {
      int mc = i / 100, rc = i % 100;
      int rr = rc / 10, ccx = rc % 10;
      int gr = r0 + rr, gc = c0 + ccx;
      float v = 0.f;
      if (gr >= 0 && gr < HH && gc >= 0 && gc < WW)
        v = y1[(m0 + mc) * HWSZ + gr * WW + gc];
      ytile[mc][rc] = v;
    }
    __syncthreads();
    for (int i = threadIdx.x; i < 4096; i += 256) {
      int mc = i >> 6, pp = i & 63;
      int qy = pp >> 3, qx = pp & 7;
      const float* wp = dww + (m0 + mc) * 9;
      float s = dwb[m0 + mc];
#pragma unroll
      for (int dy = 0; dy < 3; dy++)
#pragma unroll
        for (int dx = 0; dx < 3; dx++)
          s += wp[dy * 3 + dx] * ytile[mc][(qy + dy) * 10 + qx + dx];
      t[mc][pp] = fmaxf(s, 0.f);
    }
    __syncthreads();
    for (int mc = 0; mc < 64; mc++) {
      float in = t[mc][px];
#pragma unroll
      for (int j = 0; j < 32; j++) acc[j] += p2w[(co0 + j) * MIDC + m0 + mc] * in;
    }
  }
  int gp = (by * 8 + (px >> 3)) * WW + bx * 8 + (px & 7);
#pragma unroll
  for (int j = 0; j < 32; j++) {
    int co = co0 + j;
    int gi = (bi * CC + co) * HWSZ + gp;
    out[gi] = x2[gi] + acc[j] + p2b[co];
  }
}

extern "C" void kernel_launch(void* const* d_in, const int* in_sizes, int n_in,
                              void* d_out, int out_size, void* d_ws, size_t ws_size,
                              hipStream_t stream) {
  const float* x    = (const float*)d_in[0];
  const float* illu = (const float*)d_in[1];
  const float* ln1w = (const float*)d_in[2];
  const float* ln1b = (const float*)d_in[3];
  const float* qw   = (const float*)d_in[4];
  const float* kw   = (const float*)d_in[5];
  const float* vw   = (const float*)d_in[6];
  const float* a1w  = (const float*)d_in[7];
  const float* a2w  = (const float*)d_in[8];
  const float* a2b  = (const float*)d_in[9];
  const float* tA   = (const float*)d_in[10];
  const float* tV   = (const float*)d_in[11];
  const float* pow_ = (const float*)d_in[12];
  const float* ln2w = (const float*)d_in[13];
  const float* ln2b = (const float*)d_in[14];
  const float* p1w  = (const float*)d_in[15];
  const float* p1b  = (const float*)d_in[16];
  const float* dww  = (const float*)d_in[17];
  const float* dwb  = (const float*)d_in[18];
  const float* p2w  = (const float*)d_in[19];
  const float* p2b  = (const float*)d_in[20];
  float* out = (float*)d_out;

  // workspace layout (floats)
  float* ws   = (float*)d_ws;
  float* vbuf = ws;                       // 33,554,432  (v; later x2)
  float* r2   = ws + 33554432;
  float* qb   = r2;                       // 8,388,608
  float* kb   = qb + 8388608;             // 8,388,608
  float* a1b  = kb + 8388608;             // 8,388,608
  float* ab   = a1b + 8388608;            // 4,194,304
  float* outv = ab + 4194304;             // 16,777,216
  float* attnA = outv + 16777216;         // 4096
  float* attnK = attnA + 4096;            // 4096
  float* weff  = attnK + 4096;            // 32768
  float* dots  = weff + 32768;            // 32*296 = 9472
  short* wt    = (short*)(dots + 9472);   // 9*128*128 bf16 (73,728 floats)
  float* y1 = r2;      // per-batch FFN mid buffer, reuses q/k space
  float* xn = out;     // d_out doubles as xn f32 scratch (dead before final write)
  short* xnt = (short*)outv;  // bf16 NHWC xn; outv region is dead until k_outv

  k_ln1<<<1024, 256, 0, stream>>>(x, ln1w, ln1b, xn, xnt);
  k_wcast<<<576, 256, 0, stream>>>(kw, wt);
  k_dws2<<<32768, 256, 0, stream>>>(xn, qw, qb);
  k_dws2<<<32768, 256, 0, stream>>>(xn, a1w, a1b);
  k_kconv_mfma<<<1024, 256, 0, stream>>>(xnt, wt, kb);
  k_v1x1<<<4096, 256, 0, stream>>>(xn, vw, illu, vbuf);
  k_a2<<<1024, 256, 0, stream>>>(a1b, a2w, a2b, ab);
  k_dots<<<32 * 296, 256, 0, stream>>>(qb, kb, ab, dots);
  k_softmax<<<32, 64, 0, stream>>>(dots, tA, tV, attnA, attnK);
  k_weff<<<4, 256, 0, stream>>>(pow_, attnA, weff);
  k_outv<<<1024, 256, 0, stream>>>(attnK, vbuf, outv);
  k_x2<<<4096, 256, 0, stream>>>(x, weff, outv, vbuf);
  for (int bi = 0; bi < 4; bi++) {
    k_ln2p1<<<1024, 256, 0, stream>>>(vbuf, ln2w, ln2b, p1w, p1b, y1, bi);
    k_ffn2<<<1024, 256, 0, stream>>>(y1, dww, dwb, p2w, p2b, vbuf, out, bi);
  }
}

// Round 4
// 1305.809 us; speedup vs baseline: 9.3939x; 2.5264x over previous
//
#include <hip/hip_runtime.h>

#define BB 4
#define CC 128
#define HH 256
#define WW 256
#define HWSZ 65536
#define H2 128
#define W2 128
#define L4SZ 16384
#define MIDC 256
#define NHEADS 8

typedef __attribute__((ext_vector_type(8))) short short8;
typedef __attribute__((ext_vector_type(4))) float f32x4;
typedef __attribute__((ext_vector_type(4))) unsigned u32x4;

__device__ __forceinline__ short f2bf(float v) {
  unsigned u = __builtin_bit_cast(unsigned, v);
  u += 0x7fffu + ((u >> 16) & 1u);
  return (short)(u >> 16);
}
__device__ __forceinline__ unsigned pk2(float a, float b) {
  return (unsigned)(unsigned short)f2bf(a) | ((unsigned)(unsigned short)f2bf(b) << 16);
}
__device__ __forceinline__ float bflo(unsigned u) { return __builtin_bit_cast(float, u << 16); }
__device__ __forceinline__ float bfhi(unsigned u) { return __builtin_bit_cast(float, u & 0xffff0000u); }

// ---------------- K1: LayerNorm over channel dim; emits f32 NCHW + bf16 NHWC
__global__ __launch_bounds__(256) void k_ln1(const float* __restrict__ x,
                                             const float* __restrict__ w,
                                             const float* __restrict__ b,
                                             float* __restrict__ out,
                                             short* __restrict__ xnt) {
  int idx = blockIdx.x * 256 + threadIdx.x;  // B*HW threads
  int bi = idx >> 16;
  int p  = idx & 65535;
  const float* xp = x + (bi * CC) * HWSZ + p;
  float s = 0.f, s2 = 0.f;
  for (int c = 0; c < CC; c++) { float v = xp[c * HWSZ]; s += v; s2 += v * v; }
  float mu  = s * (1.f / CC);
  float rstd = rsqrtf(s2 * (1.f / CC) - mu * mu + 1e-5f);
  float* op = out + (bi * CC) * HWSZ + p;
  short* tp = xnt + (size_t)idx * CC;      // NHWC row for this pixel
  for (int c0 = 0; c0 < CC; c0 += 8) {
    short8 pk;
#pragma unroll
    for (int j = 0; j < 8; j++) {
      float v = (xp[(c0 + j) * HWSZ] - mu) * rstd * w[c0 + j] + b[c0 + j];
      op[(c0 + j) * HWSZ] = v;
      pk[j] = f2bf(v);
    }
    *(short8*)(tp + c0) = pk;
  }
}

// ---------------- weight cast: wt[tap][co][ci] bf16 from kw[co][ci][tap] f32
__global__ __launch_bounds__(256) void k_wcast(const float* __restrict__ kw,
                                               short* __restrict__ wt) {
  int idx = blockIdx.x * 256 + threadIdx.x;  // 9*128*128
  if (idx >= 9 * 128 * 128) return;
  int ci = idx & 127, co = (idx >> 7) & 127, tap = idx >> 14;
  wt[idx] = f2bf(kw[(co * CC + ci) * 9 + tap]);
}

// ---------------- prep1: bf16 casts of vw, p1w*lnw, p2w; s1/s2 LN-fold vectors
__global__ __launch_bounds__(256) void k_prep1(const float* __restrict__ vw,
                                               const float* __restrict__ p1w,
                                               const float* __restrict__ lnw,
                                               const float* __restrict__ lnb,
                                               const float* __restrict__ p1b,
                                               const float* __restrict__ p2w,
                                               short* __restrict__ vwb,
                                               short* __restrict__ w1p,
                                               short* __restrict__ p2wb,
                                               float* __restrict__ s1,
                                               float* __restrict__ s2f) {
  int idx = blockIdx.x * 256 + threadIdx.x;
  if (idx < 16384) vwb[idx] = f2bf(vw[idx]);
  int i2 = idx - 16384;
  if (i2 >= 0 && i2 < 32768) { int c = i2 & 127; w1p[i2] = f2bf(p1w[i2] * lnw[c]); }
  int i3 = idx - 49152;
  if (i3 >= 0 && i3 < 32768) p2wb[i3] = f2bf(p2w[i3]);
  int i4 = idx - 81920;
  if (i4 >= 0 && i4 < 256) {
    float a = 0.f, bb2 = 0.f;
    for (int c = 0; c < 128; c++) {
      a   += p1w[i4 * 128 + c] * lnw[c];
      bb2 += p1w[i4 * 128 + c] * lnb[c];
    }
    s1[i4] = a; s2f[i4] = bb2 + p1b[i4];
  }
}

// ---------------- prep2: M[b] = po @ blockdiag(attnA@attnK)  (128x128 bf16 per batch)
__global__ __launch_bounds__(256) void k_prep2(const float* __restrict__ po,
                                               const float* __restrict__ attnA,
                                               const float* __restrict__ attnK,
                                               short* __restrict__ Mb) {
  __shared__ float T[8][16][16];
  int b = blockIdx.x;
  int tid = threadIdx.x;
  for (int i = tid; i < 2048; i += 256) {
    int h = i >> 8, c = (i >> 4) & 15, cc = i & 15;
    float s = 0.f;
#pragma unroll
    for (int d = 0; d < 8; d++)
      s += attnA[((b * 8 + h) * 16 + c) * 8 + d] * attnK[((b * 8 + h) * 8 + d) * 16 + cc];
    T[h][c][cc] = s;
  }
  __syncthreads();
  for (int i = tid; i < 16384; i += 256) {
    int co = i >> 7, cj = i & 127, h = cj >> 4, cc = cj & 15;
    float s = 0.f;
#pragma unroll
    for (int c = 0; c < 16; c++) s += po[co * 128 + h * 16 + c] * T[h][c][cc];
    Mb[b * 16384 + i] = f2bf(s);
  }
}

// ---------------- K2: depthwise 3x3 stride-2 conv, reflect pad 1 (q and a1)
__global__ __launch_bounds__(256) void k_dws2(const float* __restrict__ in,
                                              const float* __restrict__ w,
                                              float* __restrict__ out) {
  int idx = blockIdx.x * 256 + threadIdx.x;  // B*C*L4
  int xo = idx & (W2 - 1);
  int t = idx >> 7;
  int yo = t & (H2 - 1); t >>= 7;
  int c = t & (CC - 1);
  int bi = t >> 7;
  const float* ip = in + (bi * CC + c) * HWSZ;
  const float* wp = w + c * 9;
  float acc = 0.f;
#pragma unroll
  for (int dy = 0; dy < 3; dy++) {
    int r = 2 * yo + dy - 1; r = r < 0 ? -r : r;
#pragma unroll
    for (int dx = 0; dx < 3; dx++) {
      int cc2 = 2 * xo + dx - 1; cc2 = cc2 < 0 ? -cc2 : cc2;
      acc += wp[dy * 3 + dx] * ip[r * WW + cc2];
    }
  }
  out[idx] = acc;
}

// ---------------- K3: dense 3x3 s2 conv 128->128 via MFMA (implicit GEMM)
__global__ __launch_bounds__(256) void k_kconv_mfma(const short* __restrict__ xnt,
                                                    const short* __restrict__ wt,
                                                    float* __restrict__ outk) {
  __shared__ short8 ldsb[1156];  // 289 pixels x 4 granules(8ci), granule-swizzled
  int blk = blockIdx.x;
  int bx = blk & 15, by = (blk >> 4) & 15, bi = blk >> 8;
  int r0 = by * 16 - 1, c0 = bx * 16 - 1;
  int lane = threadIdx.x & 63, wv = threadIdx.x >> 6;
  int px0 = wv * 16;
  int pxl = px0 + (lane & 15);
  int py = pxl >> 3, pxx = pxl & 7;
  int g = lane >> 4;
  f32x4 acc[8];
#pragma unroll
  for (int m = 0; m < 8; m++) acc[m] = (f32x4){0.f, 0.f, 0.f, 0.f};
  for (int ci0 = 0; ci0 < CC; ci0 += 32) {
    __syncthreads();
    for (int i = threadIdx.x; i < 1156; i += 256) {
      int p = i >> 2, gg = i & 3;
      int rr = p / 17, cc = p - rr * 17;
      int gr = r0 + rr; gr = gr < 0 ? -gr : gr;
      int gc = c0 + cc; gc = gc < 0 ? -gc : gc;
      int slot = gg ^ ((p >> 1) & 3);
      ldsb[p * 4 + slot] =
          *(const short8*)(xnt + (size_t)((bi * HWSZ + gr * WW + gc) * CC + ci0 + gg * 8));
    }
    __syncthreads();
#pragma unroll
    for (int tap = 0; tap < 9; tap++) {
      int dy = tap / 3, dx = tap - dy * 3;
      int p = (2 * py + dy) * 17 + 2 * pxx + dx;
      int slot = g ^ ((p >> 1) & 3);
      short8 bfrag = ldsb[p * 4 + slot];
      const short* wbase = wt + (tap * 128 + (lane & 15)) * 128 + ci0 + g * 8;
#pragma unroll
      for (int m = 0; m < 8; m++) {
        short8 afrag = *(const short8*)(wbase + m * 16 * 128);
        acc[m] = __builtin_amdgcn_mfma_f32_16x16x32_bf16(afrag, bfrag, acc[m], 0, 0, 0);
      }
    }
  }
  int oy = by * 8 + py, ox = bx * 8 + pxx;
  int rb = g * 4;
#pragma unroll
  for (int m = 0; m < 8; m++)
#pragma unroll
    for (int r = 0; r < 4; r++)
      outk[(bi * CC + m * 16 + rb + r) * L4SZ + oy * W2 + ox] = acc[m][r];
}

// ---------------- K5: 1x1 conv 128->64 + bias (a2)
__global__ __launch_bounds__(256) void k_a2(const float* __restrict__ a1,
                                            const float* __restrict__ w,
                                            const float* __restrict__ bias,
                                            float* __restrict__ ab) {
  __shared__ float t[CC][64];
  int blk = blockIdx.x;
  int bi = blk >> 8;
  int p0 = (blk & 255) * 64;
  for (int i = threadIdx.x; i < CC * 64; i += 256) {
    int ci = i >> 6, px = i & 63;
    t[ci][px] = a1[(bi * CC + ci) * L4SZ + p0 + px];
  }
  __syncthreads();
  int px = threadIdx.x & 63;
  int co0 = ((__builtin_amdgcn_readfirstlane((int)threadIdx.x)) >> 6) << 4;
  float acc[16];
#pragma unroll
  for (int j = 0; j < 16; j++) acc[j] = 0.f;
  for (int ci = 0; ci < CC; ci++) {
    float in = t[ci][px];
#pragma unroll
    for (int j = 0; j < 16; j++) acc[j] += w[(co0 + j) * CC + ci] * in;
  }
#pragma unroll
  for (int j = 0; j < 16; j++)
    ab[(bi * 64 + co0 + j) * L4SZ + p0 + px] = acc[j] + bias[co0 + j];
}

// ---------------- K6a: all 296 dot products per (b,h), one block per dot
__global__ __launch_bounds__(256) void k_dots(const float* __restrict__ q,
                                              const float* __restrict__ k,
                                              const float* __restrict__ a,
                                              float* __restrict__ dots) {
  int blk = blockIdx.x;           // 32 * 296
  int bh = blk / 296, d = blk % 296;
  int bi = bh >> 3, h = bh & 7;
  const float* qb = q + (bi * CC + h * 16) * L4SZ;
  const float* kb = k + (bi * CC + h * 16) * L4SZ;
  const float* ab = a + (bi * 64 + h * 8) * L4SZ;
  const float *ra, *rb;
  if (d < 128)      { ra = qb + (d >> 3) * L4SZ; rb = ab + (d & 7) * L4SZ; }
  else if (d < 256) { int dd = d - 128; ra = ab + (dd >> 4) * L4SZ; rb = kb + (dd & 15) * L4SZ; }
  else if (d < 272) { ra = qb + (d - 256) * L4SZ; rb = ra; }
  else if (d < 280) { ra = ab + (d - 272) * L4SZ; rb = ra; }
  else              { ra = kb + (d - 280) * L4SZ; rb = ra; }
  const float4* ra4 = (const float4*)ra;
  const float4* rb4 = (const float4*)rb;
  float s = 0.f;
#pragma unroll 4
  for (int l = threadIdx.x; l < L4SZ / 4; l += 256) {
    float4 va = ra4[l], vb = rb4[l];
    s += va.x * vb.x + va.y * vb.y + va.z * vb.z + va.w * vb.w;
  }
#pragma unroll
  for (int off = 32; off > 0; off >>= 1) s += __shfl_down(s, off);
  __shared__ float ws4[4];
  if ((threadIdx.x & 63) == 0) ws4[threadIdx.x >> 6] = s;
  __syncthreads();
  if (threadIdx.x == 0) dots[bh * 296 + d] = ws4[0] + ws4[1] + ws4[2] + ws4[3];
}

// ---------------- K6b: softmax over the dots table (tiny)
__global__ __launch_bounds__(64) void k_softmax(const float* __restrict__ dots,
                                                const float* __restrict__ tA,
                                                const float* __restrict__ tV,
                                                float* __restrict__ attnA,
                                                float* __restrict__ attnK) {
  int bh = blockIdx.x;            // 32
  int h = bh & 7;
  const float* dt = dots + bh * 296;
  float ta = tA[h], tv = tV[h];
  if (threadIdx.x < 16) {
    int c = threadIdx.x;
    float nq = fmaxf(sqrtf(dt[256 + c]), 1e-12f);
    float lg[8]; float m = -1e30f;
#pragma unroll
    for (int e = 0; e < 8; e++) {
      float na = fmaxf(sqrtf(dt[272 + e]), 1e-12f);
      lg[e] = dt[c * 8 + e] / (nq * na) * ta;
      m = fmaxf(m, lg[e]);
    }
    float sum = 0.f;
#pragma unroll
    for (int e = 0; e < 8; e++) { lg[e] = expf(lg[e] - m); sum += lg[e]; }
    float inv = 1.f / sum;
#pragma unroll
    for (int e = 0; e < 8; e++) attnA[(bh * 16 + c) * 8 + e] = lg[e] * inv;
  } else if (threadIdx.x < 24) {
    int e = threadIdx.x - 16;
    float na = fmaxf(sqrtf(dt[272 + e]), 1e-12f);
    float lg[16]; float m = -1e30f;
#pragma unroll
    for (int c = 0; c < 16; c++) {
      float nk = fmaxf(sqrtf(dt[280 + c]), 1e-12f);
      lg[c] = dt[128 + e * 16 + c] / (na * nk) * tv;
      m = fmaxf(m, lg[c]);
    }
    float sum = 0.f;
#pragma unroll
    for (int c = 0; c < 16; c++) { lg[c] = expf(lg[c] - m); sum += lg[c]; }
    float inv = 1.f / sum;
#pragma unroll
    for (int c = 0; c < 16; c++) attnK[(bh * 8 + e) * 16 + c] = lg[c] * inv;
  }
}

// ---------------- K_VX2: fused v-conv + illu + attn-apply (M@v) + residual + LN2 stats
// writes x2 f32 NCHW, x2 bf16 NHWC (u32-pair), mu, rs
__global__ __launch_bounds__(256) void k_vx2(const short* __restrict__ xnt,
                                             const float* __restrict__ illu,
                                             const float* __restrict__ x,
                                             const short* __restrict__ vwb,
                                             const short* __restrict__ Mb,
                                             float* __restrict__ x2f,
                                             u32x4* __restrict__ x2n4,
                                             float* __restrict__ mu,
                                             float* __restrict__ rs) {
  __shared__ unsigned lds[4096];  // 16KB, reused 3x
  int blk = blockIdx.x;
  int bi = blk >> 10, p0 = (blk & 1023) * 64;
  int tid = threadIdx.x, lane = tid & 63, wv = tid >> 6;
  int cl = lane & 15, g = lane >> 4;
  int px = wv * 16 + cl;
  // stage xn tile (64px x 128ci bf16), granule-swizzled
  const u32x4* xsrc = (const u32x4*)(xnt + ((size_t)(bi * HWSZ + p0) << 7));
  for (int it = 0; it < 4; it++) {
    int idx = it * 256 + tid;
    int pp = idx >> 4, gg = idx & 15;
    u32x4 v = xsrc[pp * 16 + gg];
    ((u32x4*)lds)[pp * 16 + (gg ^ (pp & 7))] = v;
  }
  __syncthreads();
  // stage 1: v = vwb @ xn
  f32x4 acc[8];
#pragma unroll
  for (int m = 0; m < 8; m++) acc[m] = (f32x4){0.f, 0.f, 0.f, 0.f};
#pragma unroll
  for (int kc = 0; kc < 4; kc++) {
    short8 bf = *(const short8*)((const short*)lds + px * 128 + (((kc * 4 + g) ^ (px & 7)) * 8));
#pragma unroll
    for (int m = 0; m < 8; m++) {
      short8 af = *(const short8*)(vwb + (m * 16 + cl) * 128 + kc * 32 + g * 8);
      acc[m] = __builtin_amdgcn_mfma_f32_16x16x32_bf16(af, bf, acc[m], 0, 0, 0);
    }
  }
  __syncthreads();
  // illu multiply, pack bf16 into swizzled v tile
#pragma unroll
  for (int m = 0; m < 8; m++) {
    int cob = m * 16 + g * 4;
    float v0 = acc[m][0] * illu[(size_t)(bi * CC + cob + 0) * HWSZ + p0 + px];
    float v1 = acc[m][1] * illu[(size_t)(bi * CC + cob + 1) * HWSZ + p0 + px];
    float v2 = acc[m][2] * illu[(size_t)(bi * CC + cob + 2) * HWSZ + p0 + px];
    float v3 = acc[m][3] * illu[(size_t)(bi * CC + cob + 3) * HWSZ + p0 + px];
    int gi = 2 * m + (g >> 1);
    unsigned* dst = lds + px * 64 + ((gi ^ (px & 7)) << 2) + (g & 1) * 2;
    dst[0] = pk2(v0, v1);
    dst[1] = pk2(v2, v3);
  }
  __syncthreads();
  // stage 2: delta = Mb[bi] @ v
  f32x4 acc2[8];
#pragma unroll
  for (int m = 0; m < 8; m++) acc2[m] = (f32x4){0.f, 0.f, 0.f, 0.f};
  const short* Mbb = Mb + bi * 16384;
#pragma unroll
  for (int kc = 0; kc < 4; kc++) {
    short8 bf = *(const short8*)((const short*)lds + px * 128 + (((kc * 4 + g) ^ (px & 7)) * 8));
#pragma unroll
    for (int m = 0; m < 8; m++) {
      short8 af = *(const short8*)(Mbb + (m * 16 + cl) * 128 + kc * 32 + g * 8);
      acc2[m] = __builtin_amdgcn_mfma_f32_16x16x32_bf16(af, bf, acc2[m], 0, 0, 0);
    }
  }
  // x add + LN stats + writes
  float s = 0.f, s2 = 0.f;
  unsigned xp[16];
#pragma unroll
  for (int m = 0; m < 8; m++) {
    float tv[4];
#pragma unroll
    for (int r = 0; r < 4; r++) {
      int co = m * 16 + g * 4 + r;
      size_t gi = (size_t)(bi * CC + co) * HWSZ + p0 + px;
      float t = x[gi] + acc2[m][r];
      x2f[gi] = t;
      tv[r] = t; s += t; s2 += t * t;
    }
    xp[2 * m]     = pk2(tv[0], tv[1]);
    xp[2 * m + 1] = pk2(tv[2], tv[3]);
  }
  s  += __shfl_xor(s, 16);  s  += __shfl_xor(s, 32);
  s2 += __shfl_xor(s2, 16); s2 += __shfl_xor(s2, 32);
  float muv = s * (1.f / 128.f);
  float rsv = rsqrtf(s2 * (1.f / 128.f) - muv * muv + 1e-5f);
  if (g == 0) { mu[bi * HWSZ + p0 + px] = muv; rs[bi * HWSZ + p0 + px] = rsv; }
  __syncthreads();
  // linear bf16 x2 tile for coalesced NHWC store
#pragma unroll
  for (int m = 0; m < 8; m++) {
    lds[px * 64 + m * 8 + g * 2 + 0] = xp[2 * m];
    lds[px * 64 + m * 8 + g * 2 + 1] = xp[2 * m + 1];
  }
  __syncthreads();
  u32x4* dst4 = x2n4 + (size_t)(bi * HWSZ + p0) * 16;
  for (int it = 0; it < 4; it++) {
    int flat = it * 256 + tid;
    dst4[flat] = ((const u32x4*)lds)[flat];
  }
}

// ---------------- K_LN2P1M: y1 = affine(w1p @ x2n) per pixel (LN folded)
__global__ __launch_bounds__(256) void k_ln2p1m(const u32x4* __restrict__ x2n4,
                                                const short* __restrict__ w1p,
                                                const float* __restrict__ s1,
                                                const float* __restrict__ s2f,
                                                const float* __restrict__ mu,
                                                const float* __restrict__ rs,
                                                u32x4* __restrict__ y1n4, int bi) {
  __shared__ unsigned lds[8192];  // 32KB: x-tile (16KB) then out-tile (32KB)
  __shared__ float stab[512];
  int p0 = blockIdx.x * 64;
  int tid = threadIdx.x, lane = tid & 63, wv = tid >> 6;
  int cl = lane & 15, g = lane >> 4;
  int px = wv * 16 + cl;
  for (int i = tid; i < 512; i += 256) stab[i] = (i < 256) ? s1[i] : s2f[i - 256];
  for (int it = 0; it < 4; it++) {
    int idx = it * 256 + tid;
    int pp = idx >> 4, gg = idx & 15;
    u32x4 v = x2n4[(size_t)(bi * HWSZ + p0 + pp) * 16 + gg];
    ((u32x4*)lds)[pp * 16 + (gg ^ (pp & 7))] = v;
  }
  __syncthreads();
  f32x4 acc[16];
#pragma unroll
  for (int m = 0; m < 16; m++) acc[m] = (f32x4){0.f, 0.f, 0.f, 0.f};
#pragma unroll
  for (int kc = 0; kc < 4; kc++) {
    short8 bf = *(const short8*)((const short*)lds + px * 128 + (((kc * 4 + g) ^ (px & 7)) * 8));
#pragma unroll
    for (int m = 0; m < 16; m++) {
      short8 af = *(const short8*)(w1p + (m * 16 + cl) * 128 + kc * 32 + g * 8);
      acc[m] = __builtin_amdgcn_mfma_f32_16x16x32_bf16(af, bf, acc[m], 0, 0, 0);
    }
  }
  float muv = mu[bi * HWSZ + p0 + px], rsv = rs[bi * HWSZ + p0 + px];
  __syncthreads();
#pragma unroll
  for (int m = 0; m < 16; m++) {
#pragma unroll
    for (int rp = 0; rp < 2; rp++) {
      int o0 = m * 16 + g * 4 + 2 * rp;
      float y0 = rsv * (acc[m][2 * rp]     - muv * stab[o0])     + stab[256 + o0];
      float y1 = rsv * (acc[m][2 * rp + 1] - muv * stab[o0 + 1]) + stab[256 + o0 + 1];
      lds[px * 128 + m * 8 + g * 2 + rp] = pk2(y0, y1);
    }
  }
  __syncthreads();
  u32x4* dst4 = y1n4 + (size_t)p0 * 32;
  for (int it = 0; it < 8; it++) {
    int flat = it * 256 + tid;
    dst4[flat] = ((const u32x4*)lds)[flat];
  }
}

// ---------------- K_FFN2M: dw3x3 + bias + relu (VALU) then p2 via MFMA + residual
__global__ __launch_bounds__(256) void k_ffn2m(const u32x4* __restrict__ y1n4,
                                               const float* __restrict__ dww,
                                               const float* __restrict__ dwb,
                                               const short* __restrict__ p2wb,
                                               const float* __restrict__ p2b,
                                               const float* __restrict__ x2f,
                                               float* __restrict__ out, int bi) {
  __shared__ unsigned yt[100 * 36];   // halo tile: [100 px][32 u32-pairs + pad]
  __shared__ unsigned t32[64 * 37];   // dw out:    [64 px][32 u32-pairs + pad]
  __shared__ float pb[128];
  int blk = blockIdx.x;
  int bx = blk & 31, by = blk >> 5;
  int r0 = by * 8 - 1, c0 = bx * 8 - 1;
  int tid = threadIdx.x, lane = tid & 63, wv = tid >> 6;
  int cl = lane & 15, g = lane >> 4;
  int px = wv * 16 + cl;
  int pp = tid & 63, grp = tid >> 6;
  int qy = pp >> 3, qx = pp & 7;
  if (tid < 128) pb[tid] = p2b[tid];
  f32x4 acc[8];
#pragma unroll
  for (int m = 0; m < 8; m++) acc[m] = (f32x4){0.f, 0.f, 0.f, 0.f};
  for (int m0 = 0; m0 < MIDC; m0 += 64) {
    __syncthreads();
    // stage y1 halo chunk (bf16 NHWC, zero pad)
    for (int i = tid; i < 800; i += 256) {
      int p = i >> 3, oct = i & 7;
      int rr = p / 10, cc2 = p - rr * 10;
      int gr = r0 + rr, gc = c0 + cc2;
      u32x4 v = (u32x4){0u, 0u, 0u, 0u};
      if (gr >= 0 && gr < HH && gc >= 0 && gc < WW)
        v = y1n4[(size_t)(gr * WW + gc) * 32 + (m0 >> 3) + oct];
      *(u32x4*)(yt + p * 36 + oct * 4) = v;
    }
    __syncthreads();
    // depthwise 3x3 + bias + relu, 16 ch per thread
    float sdw[16];
#pragma unroll
    for (int j = 0; j < 16; j++) sdw[j] = 0.f;
#pragma unroll
    for (int tap = 0; tap < 9; tap++) {
      int dy = tap / 3, dx = tap - dy * 3;
      int p = (qy + dy) * 10 + qx + dx;
      u32x4 a = *(const u32x4*)(yt + p * 36 + grp * 8);
      u32x4 b = *(const u32x4*)(yt + p * 36 + grp * 8 + 4);
      const float* wp = dww + (m0 + grp * 16) * 9 + tap;
      sdw[0]  += wp[0]   * bflo(a.x); sdw[1]  += wp[9]   * bfhi(a.x);
      sdw[2]  += wp[18]  * bflo(a.y); sdw[3]  += wp[27]  * bfhi(a.y);
      sdw[4]  += wp[36]  * bflo(a.z); sdw[5]  += wp[45]  * bfhi(a.z);
      sdw[6]  += wp[54]  * bflo(a.w); sdw[7]  += wp[63]  * bfhi(a.w);
      sdw[8]  += wp[72]  * bflo(b.x); sdw[9]  += wp[81]  * bfhi(b.x);
      sdw[10] += wp[90]  * bflo(b.y); sdw[11] += wp[99]  * bfhi(b.y);
      sdw[12] += wp[108] * bflo(b.z); sdw[13] += wp[117] * bfhi(b.z);
      sdw[14] += wp[126] * bflo(b.w); sdw[15] += wp[135] * bfhi(b.w);
    }
#pragma unroll
    for (int q = 0; q < 8; q++) {
      float v0 = fmaxf(sdw[2 * q]     + dwb[m0 + grp * 16 + 2 * q], 0.f);
      float v1 = fmaxf(sdw[2 * q + 1] + dwb[m0 + grp * 16 + 2 * q + 1], 0.f);
      t32[pp * 37 + grp * 8 + q] = pk2(v0, v1);
    }
    __syncthreads();
    // p2 MFMA partial
#pragma unroll
    for (int kc = 0; kc < 2; kc++) {
      unsigned bw0 = t32[px * 37 + kc * 16 + g * 4 + 0];
      unsigned bw1 = t32[px * 37 + kc * 16 + g * 4 + 1];
      unsigned bw2 = t32[px * 37 + kc * 16 + g * 4 + 2];
      unsigned bw3 = t32[px * 37 + kc * 16 + g * 4 + 3];
      short8 bf = __builtin_bit_cast(short8, (u32x4){bw0, bw1, bw2, bw3});
#pragma unroll
      for (int m = 0; m < 8; m++) {
        short8 af = *(const short8*)(p2wb + (m * 16 + cl) * 256 + m0 + kc * 32 + g * 8);
        acc[m] = __builtin_amdgcn_mfma_f32_16x16x32_bf16(af, bf, acc[m], 0, 0, 0);
      }
    }
  }
  int gp = (by * 8 + (px >> 3)) * WW + bx * 8 + (px & 7);
#pragma unroll
  for (int m = 0; m < 8; m++)
#pragma unroll
    for (int r = 0; r < 4; r++) {
      int co = m * 16 + g * 4 + r;
      size_t gi = (size_t)(bi * CC + co) * HWSZ + gp;
      out[gi] = x2f[gi] + acc[m][r] + pb[co];
    }
}

extern "C" void kernel_launch(void* const* d_in, const int* in_sizes, int n_in,
                              void* d_out, int out_size, void* d_ws, size_t ws_size,
                              hipStream_t stream) {
  const float* x    = (const float*)d_in[0];
  const float* illu = (const float*)d_in[1];
  const float* ln1w = (const float*)d_in[2];
  const float* ln1b = (const float*)d_in[3];
  const float* qw   = (const float*)d_in[4];
  const float* kw   = (const float*)d_in[5];
  const float* vw   = (const float*)d_in[6];
  const float* a1w  = (const float*)d_in[7];
  const float* a2w  = (const float*)d_in[8];
  const float* a2b  = (const float*)d_in[9];
  const float* tA   = (const float*)d_in[10];
  const float* tV   = (const float*)d_in[11];
  const float* pow_ = (const float*)d_in[12];
  const float* ln2w = (const float*)d_in[13];
  const float* ln2b = (const float*)d_in[14];
  const float* p1w  = (const float*)d_in[15];
  const float* p1b  = (const float*)d_in[16];
  const float* dww  = (const float*)d_in[17];
  const float* dwb  = (const float*)d_in[18];
  const float* p2w  = (const float*)d_in[19];
  const float* p2b  = (const float*)d_in[20];
  float* out = (float*)d_out;

  // workspace layout (float slots), total 79,774,208 < previous 79,815,936
  float* ws    = (float*)d_ws;
  float* x2f   = ws;                       // 33,554,432 (written by k_vx2)
  float* dots  = ws;                       // alias: 9,472 (dead before x2f written)
  short* wt    = (short*)(ws + 9472);      // 147,456 sh (dead before x2f written)
  float* qb    = ws + 33554432;            // 8,388,608
  float* kb    = qb + 8388608;             // 8,388,608
  float* a1b   = kb + 8388608;             // 8,388,608
  float* ab    = a1b + 8388608;            // 4,194,304
  short* xnt   = (short*)(ab + 4194304);   // 33,554,432 sh (16,777,216 f)
  float* sm    = ab + 4194304 + 16777216;  // smalls base
  float* attnA = sm;                       // 4096
  float* attnK = sm + 4096;                // 4096
  short* vwb   = (short*)(sm + 8192);      // 16,384 sh
  short* w1p   = (short*)(sm + 16384);     // 32,768 sh
  short* p2wb  = (short*)(sm + 32768);     // 32,768 sh
  short* Mb    = (short*)(sm + 49152);     // 65,536 sh
  float* s1    = sm + 81920;               // 256
  float* s2f   = sm + 82176;               // 256
  u32x4* x2n4  = (u32x4*)qb;               // bf16 NHWC x2 (over qb+kb, dead)
  u32x4* y1n4  = (u32x4*)a1b;              // per-batch bf16 NHWC y1 (over a1b, dead)
  float* mu    = ab;                       // 262,144 (over ab, dead)
  float* rs    = ab + 262144;              // 262,144
  float* xn    = out;                      // d_out doubles as xn f32 scratch

  k_ln1<<<1024, 256, 0, stream>>>(x, ln1w, ln1b, xn, xnt);
  k_wcast<<<576, 256, 0, stream>>>(kw, wt);
  k_prep1<<<321, 256, 0, stream>>>(vw, p1w, ln2w, ln2b, p1b, p2w, vwb, w1p, p2wb, s1, s2f);
  k_dws2<<<32768, 256, 0, stream>>>(xn, qw, qb);
  k_dws2<<<32768, 256, 0, stream>>>(xn, a1w, a1b);
  k_kconv_mfma<<<1024, 256, 0, stream>>>(xnt, wt, kb);
  k_a2<<<1024, 256, 0, stream>>>(a1b, a2w, a2b, ab);
  k_dots<<<32 * 296, 256, 0, stream>>>(qb, kb, ab, dots);
  k_softmax<<<32, 64, 0, stream>>>(dots, tA, tV, attnA, attnK);
  k_prep2<<<4, 256, 0, stream>>>(pow_, attnA, attnK, Mb);
  k_vx2<<<4096, 256, 0, stream>>>(xnt, illu, x, vwb, Mb, x2f, x2n4, mu, rs);
  for (int bi = 0; bi < 4; bi++) {
    k_ln2p1m<<<1024, 256, 0, stream>>>(x2n4, w1p, s1, s2f, mu, rs, y1n4, bi);
    k_ffn2m<<<1024, 256, 0, stream>>>(y1n4, dww, dwb, p2wb, p2b, x2f, out, bi);
  }
}

// Round 5
// 902.079 us; speedup vs baseline: 13.5982x; 1.4476x over previous
//
#include <hip/hip_runtime.h>

#define BB 4
#define CC 128
#define HH 256
#define WW 256
#define HWSZ 65536
#define H2 128
#define W2 128
#define L4SZ 16384
#define MIDC 256
#define NHEADS 8

typedef __attribute__((ext_vector_type(8))) short short8;
typedef __attribute__((ext_vector_type(4))) short s16x4;
typedef __attribute__((ext_vector_type(4))) float f32x4;
typedef __attribute__((ext_vector_type(4))) unsigned u32x4;
typedef __attribute__((ext_vector_type(2))) unsigned u32x2;

__device__ __forceinline__ short f2bf(float v) {
  unsigned u = __builtin_bit_cast(unsigned, v);
  u += 0x7fffu + ((u >> 16) & 1u);
  return (short)(u >> 16);
}
__device__ __forceinline__ unsigned pk2(float a, float b) {
  return (unsigned)(unsigned short)f2bf(a) | ((unsigned)(unsigned short)f2bf(b) << 16);
}
__device__ __forceinline__ float bflo(unsigned u) { return __builtin_bit_cast(float, u << 16); }
__device__ __forceinline__ float bfhi(unsigned u) { return __builtin_bit_cast(float, u & 0xffff0000u); }
__device__ __forceinline__ float b2f(short s) {
  return __builtin_bit_cast(float, ((unsigned)(unsigned short)s) << 16);
}

// ---------------- K1: LayerNorm over channel dim; emits bf16 NHWC only
__global__ __launch_bounds__(256) void k_ln1(const float* __restrict__ x,
                                             const float* __restrict__ w,
                                             const float* __restrict__ b,
                                             short* __restrict__ xnt) {
  int idx = blockIdx.x * 256 + threadIdx.x;  // B*HW threads
  int bi = idx >> 16;
  int p  = idx & 65535;
  const float* xp = x + (bi * CC) * HWSZ + p;
  float s = 0.f, s2 = 0.f;
  for (int c = 0; c < CC; c++) { float v = xp[c * HWSZ]; s += v; s2 += v * v; }
  float mu  = s * (1.f / CC);
  float rstd = rsqrtf(s2 * (1.f / CC) - mu * mu + 1e-5f);
  short* tp = xnt + (size_t)idx * CC;
  for (int c0 = 0; c0 < CC; c0 += 8) {
    short8 pk;
#pragma unroll
    for (int j = 0; j < 8; j++) {
      float v = (xp[(c0 + j) * HWSZ] - mu) * rstd * w[c0 + j] + b[c0 + j];
      pk[j] = f2bf(v);
    }
    *(short8*)(tp + c0) = pk;
  }
}

// ---------------- weight cast: wt[tap][co][ci] bf16 from kw[co][ci][tap] f32
__global__ __launch_bounds__(256) void k_wcast(const float* __restrict__ kw,
                                               short* __restrict__ wt) {
  int idx = blockIdx.x * 256 + threadIdx.x;  // 9*128*128
  if (idx >= 9 * 128 * 128) return;
  int ci = idx & 127, co = (idx >> 7) & 127, tap = idx >> 14;
  wt[idx] = f2bf(kw[(co * CC + ci) * 9 + tap]);
}

// ---------------- prep1: bf16 weight casts + LN-fold vectors + small transposes
__global__ __launch_bounds__(256) void k_prep1(const float* __restrict__ vw,
                                               const float* __restrict__ p1w,
                                               const float* __restrict__ lnw,
                                               const float* __restrict__ lnb,
                                               const float* __restrict__ p1b,
                                               const float* __restrict__ p2w,
                                               const float* __restrict__ qw,
                                               const float* __restrict__ a1w,
                                               const float* __restrict__ dww,
                                               short* __restrict__ vwb,
                                               short* __restrict__ w1p,
                                               short* __restrict__ p2wb,
                                               float* __restrict__ s1,
                                               float* __restrict__ s2f,
                                               float* __restrict__ qwt,
                                               float* __restrict__ a1wt,
                                               float* __restrict__ dwwt) {
  int idx = blockIdx.x * 256 + threadIdx.x;
  if (idx < 16384) vwb[idx] = f2bf(vw[idx]);
  int i2 = idx - 16384;
  if (i2 >= 0 && i2 < 32768) { int c = i2 & 127; w1p[i2] = f2bf(p1w[i2] * lnw[c]); }
  int i3 = idx - 49152;
  if (i3 >= 0 && i3 < 32768) p2wb[i3] = f2bf(p2w[i3]);
  int i4 = idx - 81920;
  if (i4 >= 0 && i4 < 256) {
    float a = 0.f, bb2 = 0.f;
    for (int c = 0; c < 128; c++) {
      a   += p1w[i4 * 128 + c] * lnw[c];
      bb2 += p1w[i4 * 128 + c] * lnb[c];
    }
    s1[i4] = a; s2f[i4] = bb2 + p1b[i4];
  }
  int i5 = idx - 82176;
  if (i5 >= 0 && i5 < 1152) { int tap = i5 >> 7, c = i5 & 127; qwt[i5] = qw[c * 9 + tap]; }
  int i6 = idx - 83328;
  if (i6 >= 0 && i6 < 1152) { int tap = i6 >> 7, c = i6 & 127; a1wt[i6] = a1w[c * 9 + tap]; }
  int i7 = idx - 84480;
  if (i7 >= 0 && i7 < 2304) { int tap = i7 / 256, c = i7 - tap * 256; dwwt[i7] = dww[c * 9 + tap]; }
}

// ---------------- prep2: M[b] = po @ blockdiag(attnA@attnK)  (128x128 bf16 per batch)
__global__ __launch_bounds__(256) void k_prep2(const float* __restrict__ po,
                                               const float* __restrict__ attnA,
                                               const float* __restrict__ attnK,
                                               short* __restrict__ Mb) {
  __shared__ float T[8][16][16];
  int b = blockIdx.x;
  int tid = threadIdx.x;
  for (int i = tid; i < 2048; i += 256) {
    int h = i >> 8, c = (i >> 4) & 15, cc = i & 15;
    float s = 0.f;
#pragma unroll
    for (int d = 0; d < 8; d++)
      s += attnA[((b * 8 + h) * 16 + c) * 8 + d] * attnK[((b * 8 + h) * 8 + d) * 16 + cc];
    T[h][c][cc] = s;
  }
  __syncthreads();
  for (int i = tid; i < 16384; i += 256) {
    int co = i >> 7, cj = i & 127, h = cj >> 4, cc = cj & 15;
    float s = 0.f;
#pragma unroll
    for (int c = 0; c < 16; c++) s += po[co * 128 + h * 16 + c] * T[h][c][cc];
    Mb[b * 16384 + i] = f2bf(s);
  }
}

// ---------------- K_DWSN: fused depthwise 3x3 s2 reflect for q AND a1 (bf16 NHWC in, bf16 [b][c][L4] out)
__global__ __launch_bounds__(256) void k_dwsn(const short* __restrict__ xnt,
                                              const float* __restrict__ qwt,
                                              const float* __restrict__ a1wt,
                                              short* __restrict__ qg,
                                              short* __restrict__ a1g) {
  int blk = blockIdx.x;                 // 1024 = b(4) x y(128) x xg(2)
  int xg = blk & 1, y = (blk >> 1) & 127, b = blk >> 8;
  int oct = threadIdx.x & 15, pxq = threadIdx.x >> 4;  // pxq 0..15
  int x0 = xg * 64 + pxq * 4;
  float aq[4][8], aa[4][8];
#pragma unroll
  for (int j = 0; j < 4; j++)
#pragma unroll
    for (int c = 0; c < 8; c++) { aq[j][c] = 0.f; aa[j][c] = 0.f; }
#pragma unroll
  for (int tap = 0; tap < 9; tap++) {
    int dy = tap / 3, dx = tap - 3 * dy;
    int ry = 2 * y + dy - 1; ry = ry < 0 ? -ry : ry;
    float4 wq0 = *(const float4*)(qwt + tap * 128 + oct * 8);
    float4 wq1 = *(const float4*)(qwt + tap * 128 + oct * 8 + 4);
    float4 wa0 = *(const float4*)(a1wt + tap * 128 + oct * 8);
    float4 wa1 = *(const float4*)(a1wt + tap * 128 + oct * 8 + 4);
#pragma unroll
    for (int jq = 0; jq < 4; jq++) {
      int ix = 2 * (x0 + jq) + dx - 1; ix = ix < 0 ? -ix : ix;
      short8 xv = *(const short8*)(xnt + (size_t)((b * HWSZ + ry * WW + ix) * CC) + oct * 8);
      float f0 = b2f(xv[0]), f1 = b2f(xv[1]), f2 = b2f(xv[2]), f3 = b2f(xv[3]);
      float f4 = b2f(xv[4]), f5 = b2f(xv[5]), f6 = b2f(xv[6]), f7 = b2f(xv[7]);
      aq[jq][0] += wq0.x * f0; aq[jq][1] += wq0.y * f1; aq[jq][2] += wq0.z * f2; aq[jq][3] += wq0.w * f3;
      aq[jq][4] += wq1.x * f4; aq[jq][5] += wq1.y * f5; aq[jq][6] += wq1.z * f6; aq[jq][7] += wq1.w * f7;
      aa[jq][0] += wa0.x * f0; aa[jq][1] += wa0.y * f1; aa[jq][2] += wa0.z * f2; aa[jq][3] += wa0.w * f3;
      aa[jq][4] += wa1.x * f4; aa[jq][5] += wa1.y * f5; aa[jq][6] += wa1.z * f6; aa[jq][7] += wa1.w * f7;
    }
  }
  int pb = y * 128 + x0;
#pragma unroll
  for (int j = 0; j < 8; j++) {
    s16x4 vq = { f2bf(aq[0][j]), f2bf(aq[1][j]), f2bf(aq[2][j]), f2bf(aq[3][j]) };
    s16x4 va = { f2bf(aa[0][j]), f2bf(aa[1][j]), f2bf(aa[2][j]), f2bf(aa[3][j]) };
    *(s16x4*)(qg  + (size_t)(b * CC + oct * 8 + j) * L4SZ + pb) = vq;
    *(s16x4*)(a1g + (size_t)(b * CC + oct * 8 + j) * L4SZ + pb) = va;
  }
}

// ---------------- K3: dense 3x3 s2 conv 128->128 via MFMA, bf16 out
__global__ __launch_bounds__(256) void k_kconv_mfma(const short* __restrict__ xnt,
                                                    const short* __restrict__ wt,
                                                    short* __restrict__ kg) {
  __shared__ short8 ldsb[1156];  // 289 pixels x 4 granules(8ci), granule-swizzled
  int blk = blockIdx.x;
  int bx = blk & 15, by = (blk >> 4) & 15, bi = blk >> 8;
  int r0 = by * 16 - 1, c0 = bx * 16 - 1;
  int lane = threadIdx.x & 63, wv = threadIdx.x >> 6;
  int px0 = wv * 16;
  int pxl = px0 + (lane & 15);
  int py = pxl >> 3, pxx = pxl & 7;
  int g = lane >> 4;
  f32x4 acc[8];
#pragma unroll
  for (int m = 0; m < 8; m++) acc[m] = (f32x4){0.f, 0.f, 0.f, 0.f};
  for (int ci0 = 0; ci0 < CC; ci0 += 32) {
    __syncthreads();
    for (int i = threadIdx.x; i < 1156; i += 256) {
      int p = i >> 2, gg = i & 3;
      int rr = p / 17, cc = p - rr * 17;
      int gr = r0 + rr; gr = gr < 0 ? -gr : gr;
      int gc = c0 + cc; gc = gc < 0 ? -gc : gc;
      int slot = gg ^ ((p >> 1) & 3);
      ldsb[p * 4 + slot] =
          *(const short8*)(xnt + (size_t)((bi * HWSZ + gr * WW + gc) * CC + ci0 + gg * 8));
    }
    __syncthreads();
#pragma unroll
    for (int tap = 0; tap < 9; tap++) {
      int dy = tap / 3, dx = tap - dy * 3;
      int p = (2 * py + dy) * 17 + 2 * pxx + dx;
      int slot = g ^ ((p >> 1) & 3);
      short8 bfrag = ldsb[p * 4 + slot];
      const short* wbase = wt + (tap * 128 + (lane & 15)) * 128 + ci0 + g * 8;
#pragma unroll
      for (int m = 0; m < 8; m++) {
        short8 afrag = *(const short8*)(wbase + m * 16 * 128);
        acc[m] = __builtin_amdgcn_mfma_f32_16x16x32_bf16(afrag, bfrag, acc[m], 0, 0, 0);
      }
    }
  }
  int oy = by * 8 + py, ox = bx * 8 + pxx;
  int rb = g * 4;
#pragma unroll
  for (int m = 0; m < 8; m++)
#pragma unroll
    for (int r = 0; r < 4; r++)
      kg[(size_t)(bi * CC + m * 16 + rb + r) * L4SZ + oy * W2 + ox] = f2bf(acc[m][r]);
}

// ---------------- K5: 1x1 conv 128->64 + bias (a2), bf16 in/out
__global__ __launch_bounds__(256) void k_a2(const short* __restrict__ a1g,
                                            const float* __restrict__ w,
                                            const float* __restrict__ bias,
                                            short* __restrict__ ab) {
  __shared__ float t[CC][64];
  int blk = blockIdx.x;
  int bi = blk >> 8;
  int p0 = (blk & 255) * 64;
  for (int i = threadIdx.x; i < CC * 64; i += 256) {
    int ci = i >> 6, px = i & 63;
    t[ci][px] = b2f(a1g[(size_t)(bi * CC + ci) * L4SZ + p0 + px]);
  }
  __syncthreads();
  int px = threadIdx.x & 63;
  int co0 = ((__builtin_amdgcn_readfirstlane((int)threadIdx.x)) >> 6) << 4;
  float acc[16];
#pragma unroll
  for (int j = 0; j < 16; j++) acc[j] = 0.f;
  for (int ci = 0; ci < CC; ci++) {
    float in = t[ci][px];
#pragma unroll
    for (int j = 0; j < 16; j++) acc[j] += w[(co0 + j) * CC + ci] * in;
  }
#pragma unroll
  for (int j = 0; j < 16; j++)
    ab[(size_t)(bi * 64 + co0 + j) * L4SZ + p0 + px] = f2bf(acc[j] + bias[co0 + j]);
}

// ---------------- K_GRAM: all attention dot products via MFMA
// tiles: 0: q.a  1: a.k  2: q.q  3: k.k  4: a.a  (rows/cols per 16x16 C layout)
__global__ __launch_bounds__(256) void k_gram(const short* __restrict__ qg,
                                              const short* __restrict__ kg,
                                              const short* __restrict__ ag,
                                              float* __restrict__ partial) {
  __shared__ float red[4][1280];
  int blk = blockIdx.x;              // 256 = bh(32) x chunk(8)
  int bh = blk >> 3, chunk = blk & 7;
  int b = bh >> 3, h = bh & 7;
  int tid = threadIdx.x, lane = tid & 63, wv = tid >> 6;
  int cl = lane & 15, g = lane >> 4;
  const short* qb = qg + (size_t)(b * 128 + h * 16 + cl) * L4SZ;
  const short* kb = kg + (size_t)(b * 128 + h * 16 + cl) * L4SZ;
  const short* ar = ag + (size_t)(b * 64 + h * 8 + cl) * L4SZ;  // cl>=8 reads pad region
  int k0 = chunk * 2048 + wv * 512 + g * 8;
  f32x4 t0 = {0,0,0,0}, t1 = {0,0,0,0}, t2 = {0,0,0,0}, t3 = {0,0,0,0}, t4 = {0,0,0,0};
#pragma unroll 4
  for (int ks = 0; ks < 16; ks++) {
    int ko = k0 + ks * 32;
    short8 fq = *(const short8*)(qb + ko);
    short8 fk = *(const short8*)(kb + ko);
    short8 fa = *(const short8*)(ar + ko);
    t0 = __builtin_amdgcn_mfma_f32_16x16x32_bf16(fq, fa, t0, 0, 0, 0);
    t1 = __builtin_amdgcn_mfma_f32_16x16x32_bf16(fa, fk, t1, 0, 0, 0);
    t2 = __builtin_amdgcn_mfma_f32_16x16x32_bf16(fq, fq, t2, 0, 0, 0);
    t3 = __builtin_amdgcn_mfma_f32_16x16x32_bf16(fk, fk, t3, 0, 0, 0);
    t4 = __builtin_amdgcn_mfma_f32_16x16x32_bf16(fa, fa, t4, 0, 0, 0);
  }
#pragma unroll
  for (int r = 0; r < 4; r++) {
    int flat = (g * 4 + r) * 16 + cl;
    red[wv][flat]        = t0[r];
    red[wv][256 + flat]  = t1[r];
    red[wv][512 + flat]  = t2[r];
    red[wv][768 + flat]  = t3[r];
    red[wv][1024 + flat] = t4[r];
  }
  __syncthreads();
  float* po = partial + (size_t)(bh * 8 + chunk) * 1280;
  for (int i = tid; i < 1280; i += 256)
    po[i] = red[0][i] + red[1][i] + red[2][i] + red[3][i];
}

// ---------------- K6b: reduce partials + softmax
__global__ __launch_bounds__(64) void k_softmax2(const float* __restrict__ partial,
                                                 const float* __restrict__ tA,
                                                 const float* __restrict__ tV,
                                                 float* __restrict__ attnA,
                                                 float* __restrict__ attnK) {
  __shared__ float S[1280];
  int bh = blockIdx.x;            // 32
  int h = bh & 7;
  for (int i = threadIdx.x; i < 1280; i += 64) {
    float s = 0.f;
    for (int c = 0; c < 8; c++) s += partial[(size_t)(bh * 8 + c) * 1280 + i];
    S[i] = s;
  }
  __syncthreads();
  float ta = tA[h], tv = tV[h];
  if (threadIdx.x < 16) {
    int c = threadIdx.x;
    float nq = fmaxf(sqrtf(S[512 + c * 17]), 1e-12f);
    float lg[8]; float m = -1e30f;
#pragma unroll
    for (int e = 0; e < 8; e++) {
      float na = fmaxf(sqrtf(S[1024 + e * 17]), 1e-12f);
      lg[e] = S[c * 16 + e] / (nq * na) * ta;
      m = fmaxf(m, lg[e]);
    }
    float sum = 0.f;
#pragma unroll
    for (int e = 0; e < 8; e++) { lg[e] = expf(lg[e] - m); sum += lg[e]; }
    float inv = 1.f / sum;
#pragma unroll
    for (int e = 0; e < 8; e++) attnA[(bh * 16 + c) * 8 + e] = lg[e] * inv;
  } else if (threadIdx.x < 24) {
    int e = threadIdx.x - 16;
    float na = fmaxf(sqrtf(S[1024 + e * 17]), 1e-12f);
    float lg[16]; float m = -1e30f;
#pragma unroll
    for (int c = 0; c < 16; c++) {
      float nk = fmaxf(sqrtf(S[768 + c * 17]), 1e-12f);
      lg[c] = S[256 + e * 16 + c] / (na * nk) * tv;
      m = fmaxf(m, lg[c]);
    }
    float sum = 0.f;
#pragma unroll
    for (int c = 0; c < 16; c++) { lg[c] = expf(lg[c] - m); sum += lg[c]; }
    float inv = 1.f / sum;
#pragma unroll
    for (int c = 0; c < 16; c++) attnK[(bh * 8 + e) * 16 + c] = lg[c] * inv;
  }
}

// ---------------- K_VX2: fused v-conv + illu + attn-apply (M@v) + residual + LN2 stats
// writes x2 bf16 NHWC (u32x4), mu, rs  (no f32 x2)
__global__ __launch_bounds__(256) void k_vx2(const short* __restrict__ xnt,
                                             const float* __restrict__ illu,
                                             const float* __restrict__ x,
                                             const short* __restrict__ vwb,
                                             const short* __restrict__ Mb,
                                             u32x4* __restrict__ x2n4,
                                             float* __restrict__ mu,
                                             float* __restrict__ rs) {
  __shared__ unsigned lds[4608];
  int blk = blockIdx.x;
  int bi = blk >> 10, p0 = (blk & 1023) * 64;
  int tid = threadIdx.x, lane = tid & 63, wv = tid >> 6;
  int cl = lane & 15, g = lane >> 4;
  int px = wv * 16 + cl;
  const u32x4* xsrc = (const u32x4*)(xnt + ((size_t)(bi * HWSZ + p0) << 7));
  for (int it = 0; it < 4; it++) {
    int idx = it * 256 + tid;
    int pp = idx >> 4, gg = idx & 15;
    u32x4 v = xsrc[pp * 16 + gg];
    ((u32x4*)lds)[pp * 16 + (gg ^ (pp & 7))] = v;
  }
  __syncthreads();
  f32x4 acc[8];
#pragma unroll
  for (int m = 0; m < 8; m++) acc[m] = (f32x4){0.f, 0.f, 0.f, 0.f};
#pragma unroll
  for (int kc = 0; kc < 4; kc++) {
    short8 bf = *(const short8*)((const short*)lds + px * 128 + (((kc * 4 + g) ^ (px & 7)) * 8));
#pragma unroll
    for (int m = 0; m < 8; m++) {
      short8 af = *(const short8*)(vwb + (m * 16 + cl) * 128 + kc * 32 + g * 8);
      acc[m] = __builtin_amdgcn_mfma_f32_16x16x32_bf16(af, bf, acc[m], 0, 0, 0);
    }
  }
  __syncthreads();
#pragma unroll
  for (int m = 0; m < 8; m++) {
    int cob = m * 16 + g * 4;
    float v0 = acc[m][0] * illu[(size_t)(bi * CC + cob + 0) * HWSZ + p0 + px];
    float v1 = acc[m][1] * illu[(size_t)(bi * CC + cob + 1) * HWSZ + p0 + px];
    float v2 = acc[m][2] * illu[(size_t)(bi * CC + cob + 2) * HWSZ + p0 + px];
    float v3 = acc[m][3] * illu[(size_t)(bi * CC + cob + 3) * HWSZ + p0 + px];
    int gi = 2 * m + (g >> 1);
    unsigned* dst = lds + px * 64 + ((gi ^ (px & 7)) << 2) + (g & 1) * 2;
    dst[0] = pk2(v0, v1);
    dst[1] = pk2(v2, v3);
  }
  __syncthreads();
  f32x4 acc2[8];
#pragma unroll
  for (int m = 0; m < 8; m++) acc2[m] = (f32x4){0.f, 0.f, 0.f, 0.f};
  const short* Mbb = Mb + bi * 16384;
#pragma unroll
  for (int kc = 0; kc < 4; kc++) {
    short8 bf = *(const short8*)((const short*)lds + px * 128 + (((kc * 4 + g) ^ (px & 7)) * 8));
#pragma unroll
    for (int m = 0; m < 8; m++) {
      short8 af = *(const short8*)(Mbb + (m * 16 + cl) * 128 + kc * 32 + g * 8);
      acc2[m] = __builtin_amdgcn_mfma_f32_16x16x32_bf16(af, bf, acc2[m], 0, 0, 0);
    }
  }
  float s = 0.f, s2 = 0.f;
  unsigned xp[16];
#pragma unroll
  for (int m = 0; m < 8; m++) {
    float tv[4];
#pragma unroll
    for (int r = 0; r < 4; r++) {
      int co = m * 16 + g * 4 + r;
      size_t gi = (size_t)(bi * CC + co) * HWSZ + p0 + px;
      float t = x[gi] + acc2[m][r];
      tv[r] = t; s += t; s2 += t * t;
    }
    xp[2 * m]     = pk2(tv[0], tv[1]);
    xp[2 * m + 1] = pk2(tv[2], tv[3]);
  }
  s  += __shfl_xor(s, 16);  s  += __shfl_xor(s, 32);
  s2 += __shfl_xor(s2, 16); s2 += __shfl_xor(s2, 32);
  float muv = s * (1.f / 128.f);
  float rsv = rsqrtf(s2 * (1.f / 128.f) - muv * muv + 1e-5f);
  if (g == 0) { mu[bi * HWSZ + p0 + px] = muv; rs[bi * HWSZ + p0 + px] = rsv; }
  __syncthreads();
#pragma unroll
  for (int m = 0; m < 8; m++) {
    lds[px * 68 + m * 8 + g * 2 + 0] = xp[2 * m];
    lds[px * 68 + m * 8 + g * 2 + 1] = xp[2 * m + 1];
  }
  __syncthreads();
  u32x4* dst4 = x2n4 + (size_t)(bi * HWSZ + p0) * 16;
  for (int it = 0; it < 4; it++) {
    int flat = it * 256 + tid;
    int pp = flat >> 4, j = flat & 15;
    dst4[flat] = *(const u32x4*)(lds + pp * 68 + j * 4);
  }
}

// ---------------- K_FFN: fused LN2+p1 (MFMA, halo recompute) + dw3x3+relu + p2 (MFMA) + bf16 residual
__global__ __launch_bounds__(256) void k_ffn(const u32x4* __restrict__ x2n4,
                                             const float* __restrict__ mu,
                                             const float* __restrict__ rs,
                                             const short* __restrict__ w1p,
                                             const float* __restrict__ s1,
                                             const float* __restrict__ s2f,
                                             const float* __restrict__ dwwt,
                                             const float* __restrict__ dwb,
                                             const short* __restrict__ p2wb,
                                             const float* __restrict__ p2b,
                                             float* __restrict__ out) {
  __shared__ u32x4 xt[1792];          // 112 halo px x 16 granules (swizzled)   28.7KB
  __shared__ short y1t[15680];        // [112 px][140 shorts] (128 mid used)    31.4KB
  __shared__ u32x4 dwt[1024];         // [64 out px][16 granules] swizzled      16KB
  __shared__ float smu[112], srs[112], smk[112];
  int blk = blockIdx.x;               // 4096 = b(4) x ty(32) x tx(32)
  int tx = blk & 31, ty = (blk >> 5) & 31, b = blk >> 10;
  int tid = threadIdx.x, lane = tid & 63, wv = tid >> 6;
  int cl = lane & 15, g = lane >> 4;
  for (int i = tid; i < 112; i += 256) {
    int rr = i / 10, cc = i - rr * 10;
    int gr = ty * 8 - 1 + rr, gc = tx * 8 - 1 + cc;
    bool val = (i < 100) && gr >= 0 && gr < HH && gc >= 0 && gc < WW;
    smu[i] = val ? mu[b * HWSZ + gr * WW + gc] : 0.f;
    srs[i] = val ? rs[b * HWSZ + gr * WW + gc] : 0.f;
    smk[i] = val ? 1.f : 0.f;
  }
  for (int i = tid; i < 1792; i += 256) {
    int p = i >> 4, gg = i & 15;
    int rr = p / 10, cc = p - rr * 10;
    int gr = ty * 8 - 1 + rr, gc = tx * 8 - 1 + cc;
    u32x4 v = (u32x4){0u, 0u, 0u, 0u};
    if (p < 100 && gr >= 0 && gr < HH && gc >= 0 && gc < WW)
      v = x2n4[(size_t)(b * HWSZ + gr * WW + gc) * 16 + gg];
    xt[p * 16 + (gg ^ (p & 7))] = v;
  }
  __syncthreads();
  f32x4 acc2[2][4];
#pragma unroll
  for (int mt = 0; mt < 2; mt++)
#pragma unroll
    for (int n = 0; n < 4; n++) acc2[mt][n] = (f32x4){0.f, 0.f, 0.f, 0.f};
  for (int ch = 0; ch < 2; ch++) {
    // ---- p1 GEMM (128 mid x 112 px, K=128) + LN2 affine fold
    f32x4 a1c[2][7];
#pragma unroll
    for (int mt = 0; mt < 2; mt++)
#pragma unroll
      for (int n = 0; n < 7; n++) a1c[mt][n] = (f32x4){0.f, 0.f, 0.f, 0.f};
#pragma unroll
    for (int kc = 0; kc < 4; kc++) {
      short8 af0 = *(const short8*)(w1p + (ch * 128 + wv * 32 + cl) * 128 + kc * 32 + g * 8);
      short8 af1 = *(const short8*)(w1p + (ch * 128 + wv * 32 + 16 + cl) * 128 + kc * 32 + g * 8);
#pragma unroll
      for (int n = 0; n < 7; n++) {
        int px = n * 16 + cl;
        short8 bf = *(const short8*)((const short*)xt + px * 128 + (((kc * 4 + g) ^ (px & 7)) * 8));
        a1c[0][n] = __builtin_amdgcn_mfma_f32_16x16x32_bf16(af0, bf, a1c[0][n], 0, 0, 0);
        a1c[1][n] = __builtin_amdgcn_mfma_f32_16x16x32_bf16(af1, bf, a1c[1][n], 0, 0, 0);
      }
    }
#pragma unroll
    for (int mt = 0; mt < 2; mt++)
#pragma unroll
      for (int n = 0; n < 7; n++) {
        int px = n * 16 + cl;
        int cl0 = wv * 32 + mt * 16 + g * 4;      // within-chunk mid index
        int c0g = ch * 128 + cl0;                 // global mid index
        float mv = smu[px], rv = srs[px], mk = smk[px];
        float y0 = (rv * (a1c[mt][n][0] - mv * s1[c0g + 0]) + s2f[c0g + 0]) * mk;
        float y1 = (rv * (a1c[mt][n][1] - mv * s1[c0g + 1]) + s2f[c0g + 1]) * mk;
        float y2 = (rv * (a1c[mt][n][2] - mv * s1[c0g + 2]) + s2f[c0g + 2]) * mk;
        float y3 = (rv * (a1c[mt][n][3] - mv * s1[c0g + 3]) + s2f[c0g + 3]) * mk;
        *(unsigned*)(y1t + px * 140 + cl0 + 0) = pk2(y0, y1);
        *(unsigned*)(y1t + px * 140 + cl0 + 2) = pk2(y2, y3);
      }
    __syncthreads();
    // ---- depthwise 3x3 + bias + relu (zero pad via border mask already in y1t)
    {
      int pp = tid & 63, grp = wv;
      int qy = pp >> 3, qx = pp & 7;
      float sdw[32];
#pragma unroll
      for (int j = 0; j < 32; j++) sdw[j] = 0.f;
#pragma unroll
      for (int tap = 0; tap < 9; tap++) {
        int dy = tap / 3, dx = tap - 3 * dy;
        int p = (qy + dy) * 10 + qx + dx;
        const short* yb = y1t + p * 140 + grp * 32;
        const float* wp = dwwt + tap * 256 + ch * 128 + grp * 32;
#pragma unroll
        for (int q2 = 0; q2 < 8; q2++) {
          u32x2 vv = *(const u32x2*)(yb + q2 * 4);
          sdw[q2 * 4 + 0] += wp[q2 * 4 + 0] * bflo(vv.x);
          sdw[q2 * 4 + 1] += wp[q2 * 4 + 1] * bfhi(vv.x);
          sdw[q2 * 4 + 2] += wp[q2 * 4 + 2] * bflo(vv.y);
          sdw[q2 * 4 + 3] += wp[q2 * 4 + 3] * bfhi(vv.y);
        }
      }
      const float* db = dwb + ch * 128 + grp * 32;
#pragma unroll
      for (int q = 0; q < 4; q++) {
        u32x4 pkv;
        pkv.x = pk2(fmaxf(sdw[q * 8 + 0] + db[q * 8 + 0], 0.f), fmaxf(sdw[q * 8 + 1] + db[q * 8 + 1], 0.f));
        pkv.y = pk2(fmaxf(sdw[q * 8 + 2] + db[q * 8 + 2], 0.f), fmaxf(sdw[q * 8 + 3] + db[q * 8 + 3], 0.f));
        pkv.z = pk2(fmaxf(sdw[q * 8 + 4] + db[q * 8 + 4], 0.f), fmaxf(sdw[q * 8 + 5] + db[q * 8 + 5], 0.f));
        pkv.w = pk2(fmaxf(sdw[q * 8 + 6] + db[q * 8 + 6], 0.f), fmaxf(sdw[q * 8 + 7] + db[q * 8 + 7], 0.f));
        dwt[pp * 16 + ((grp * 4 + q) ^ (pp & 7))] = pkv;
      }
    }
    __syncthreads();
    // ---- p2 partial (128 co x 64 px, K=128 this chunk)
#pragma unroll
    for (int kc = 0; kc < 4; kc++) {
      short8 af0 = *(const short8*)(p2wb + (wv * 32 + cl) * 256 + ch * 128 + kc * 32 + g * 8);
      short8 af1 = *(const short8*)(p2wb + (wv * 32 + 16 + cl) * 256 + ch * 128 + kc * 32 + g * 8);
#pragma unroll
      for (int n = 0; n < 4; n++) {
        int px = n * 16 + cl;
        short8 bf = __builtin_bit_cast(short8, dwt[px * 16 + ((kc * 4 + g) ^ (px & 7))]);
        acc2[0][n] = __builtin_amdgcn_mfma_f32_16x16x32_bf16(af0, bf, acc2[0][n], 0, 0, 0);
        acc2[1][n] = __builtin_amdgcn_mfma_f32_16x16x32_bf16(af1, bf, acc2[1][n], 0, 0, 0);
      }
    }
  }
  // ---- epilogue: out = bf16(x2) + p2 + p2b
  const short* xb = (const short*)xt;
#pragma unroll
  for (int mt = 0; mt < 2; mt++)
#pragma unroll
    for (int n = 0; n < 4; n++) {
      int px = n * 16 + cl;
      int p_h = (px >> 3) * 10 + (px & 7) + 11;
      int oy = ty * 8 + (px >> 3), ox = tx * 8 + (px & 7);
#pragma unroll
      for (int r = 0; r < 4; r++) {
        int co = wv * 32 + mt * 16 + g * 4 + r;
        float xv = b2f(xb[p_h * 128 + (((co >> 3) ^ (p_h & 7)) * 8) + (co & 7)]);
        out[(size_t)(b * CC + co) * HWSZ + oy * WW + ox] = xv + acc2[mt][n][r] + p2b[co];
      }
    }
}

extern "C" void kernel_launch(void* const* d_in, const int* in_sizes, int n_in,
                              void* d_out, int out_size, void* d_ws, size_t ws_size,
                              hipStream_t stream) {
  const float* x    = (const float*)d_in[0];
  const float* illu = (const float*)d_in[1];
  const float* ln1w = (const float*)d_in[2];
  const float* ln1b = (const float*)d_in[3];
  const float* qw   = (const float*)d_in[4];
  const float* kw   = (const float*)d_in[5];
  const float* vw   = (const float*)d_in[6];
  const float* a1w  = (const float*)d_in[7];
  const float* a2w  = (const float*)d_in[8];
  const float* a2b  = (const float*)d_in[9];
  const float* tA   = (const float*)d_in[10];
  const float* tV   = (const float*)d_in[11];
  const float* pow_ = (const float*)d_in[12];
  const float* ln2w = (const float*)d_in[13];
  const float* ln2b = (const float*)d_in[14];
  const float* p1w  = (const float*)d_in[15];
  const float* p1b  = (const float*)d_in[16];
  const float* dww  = (const float*)d_in[17];
  const float* dwb  = (const float*)d_in[18];
  const float* p2w  = (const float*)d_in[19];
  const float* p2b  = (const float*)d_in[20];
  float* out = (float*)d_out;

  // workspace layout (float slots), total ~49.4M floats = 198MB
  float* ws    = (float*)d_ws;
  short* xnt   = (short*)ws;                     // 33,554,432 shorts
  short* qg    = (short*)(ws + 16777216);        // 8,388,608 shorts
  short* kg    = (short*)(ws + 20971520);        // 8,388,608 shorts
  short* a1g   = (short*)(ws + 25165824);        // 8,388,608 shorts
  short* ab    = (short*)(ws + 29360128);        // 4,194,304 shorts (+512KB pad after)
  float* partial = ws + 31588352;                // 327,680
  u32x4* x2n4  = (u32x4*)(ws + 31916032);        // 16,777,216 floats worth of bf16 NHWC
  float* mu    = ws + 48693248;                  // 262,144
  float* rs    = ws + 48955392;                  // 262,144
  float* attnA = ws + 49217536;                  // 4,096
  float* attnK = ws + 49221632;                  // 4,096
  short* vwb   = (short*)(ws + 49225728);        // 16,384 shorts
  short* w1p   = (short*)(ws + 49233920);        // 32,768 shorts
  short* p2wb  = (short*)(ws + 49250304);        // 32,768 shorts
  short* Mb    = (short*)(ws + 49266688);        // 65,536 shorts
  float* s1    = ws + 49299456;                  // 256
  float* s2f   = ws + 49299712;                  // 256
  short* wt    = (short*)(ws + 49299968);        // 147,456 shorts
  float* qwt   = ws + 49373696;                  // 1,152
  float* a1wt  = ws + 49374848;                  // 1,152
  float* dwwt  = ws + 49376000;                  // 2,304

  k_ln1<<<1024, 256, 0, stream>>>(x, ln1w, ln1b, xnt);
  k_wcast<<<576, 256, 0, stream>>>(kw, wt);
  k_prep1<<<340, 256, 0, stream>>>(vw, p1w, ln2w, ln2b, p1b, p2w, qw, a1w, dww,
                                   vwb, w1p, p2wb, s1, s2f, qwt, a1wt, dwwt);
  k_dwsn<<<1024, 256, 0, stream>>>(xnt, qwt, a1wt, qg, a1g);
  k_kconv_mfma<<<1024, 256, 0, stream>>>(xnt, wt, kg);
  k_a2<<<1024, 256, 0, stream>>>(a1g, a2w, a2b, ab);
  k_gram<<<256, 256, 0, stream>>>(qg, kg, ab, partial);
  k_softmax2<<<32, 64, 0, stream>>>(partial, tA, tV, attnA, attnK);
  k_prep2<<<4, 256, 0, stream>>>(pow_, attnA, attnK, Mb);
  k_vx2<<<4096, 256, 0, stream>>>(xnt, illu, x, vwb, Mb, x2n4, mu, rs);
  k_ffn<<<4096, 256, 0, stream>>>(x2n4, mu, rs, w1p, s1, s2f, dwwt, dwb, p2wb, p2b, out);
}

// Round 6
// 739.304 us; speedup vs baseline: 16.5921x; 1.2202x over previous
//
#include <hip/hip_runtime.h>

#define BB 4
#define CC 128
#define HH 256
#define WW 256
#define HWSZ 65536
#define H2 128
#define W2 128
#define L4SZ 16384
#define MIDC 256
#define NHEADS 8

typedef __attribute__((ext_vector_type(8))) short short8;
typedef __attribute__((ext_vector_type(4))) short s16x4;
typedef __attribute__((ext_vector_type(4))) float f32x4;
typedef __attribute__((ext_vector_type(4))) unsigned u32x4;
typedef __attribute__((ext_vector_type(2))) unsigned u32x2;

__device__ __forceinline__ short f2bf(float v) {
  unsigned u = __builtin_bit_cast(unsigned, v);
  u += 0x7fffu + ((u >> 16) & 1u);
  return (short)(u >> 16);
}
__device__ __forceinline__ unsigned pk2(float a, float b) {
  return (unsigned)(unsigned short)f2bf(a) | ((unsigned)(unsigned short)f2bf(b) << 16);
}
__device__ __forceinline__ float bflo(unsigned u) { return __builtin_bit_cast(float, u << 16); }
__device__ __forceinline__ float bfhi(unsigned u) { return __builtin_bit_cast(float, u & 0xffff0000u); }
__device__ __forceinline__ float b2f(short s) {
  return __builtin_bit_cast(float, ((unsigned)(unsigned short)s) << 16);
}

// ---------------- K1: LayerNorm; 64 px/block, regs hold values, coalesced NHWC store
__global__ __launch_bounds__(256) void k_ln1(const float* __restrict__ x,
                                             const float* __restrict__ w,
                                             const float* __restrict__ b,
                                             short* __restrict__ xnt) {
  __shared__ float reds[4][64], red2[4][64];
  __shared__ u32x4 tile[1024];   // 16KB, [px][16 granules] XOR-swizzled
  int blk = blockIdx.x;          // 4096 = b(4) x 1024 tiles of 64 px
  int bi = blk >> 10, p0 = (blk & 1023) * 64;
  int tid = threadIdx.x, pxl = tid & 63, cs = tid >> 6;
  const float* xp = x + (size_t)(bi * CC + cs * 32) * HWSZ + p0 + pxl;
  float v[32];
  float s = 0.f, s2 = 0.f;
#pragma unroll
  for (int j = 0; j < 32; j++) { float t = xp[j * HWSZ]; v[j] = t; s += t; s2 += t * t; }
  reds[cs][pxl] = s; red2[cs][pxl] = s2;
  __syncthreads();
  float st  = reds[0][pxl] + reds[1][pxl] + reds[2][pxl] + reds[3][pxl];
  float s2t = red2[0][pxl] + red2[1][pxl] + red2[2][pxl] + red2[3][pxl];
  float mu = st * (1.f / CC);
  float rstd = rsqrtf(s2t * (1.f / CC) - mu * mu + 1e-5f);
#pragma unroll
  for (int q = 0; q < 4; q++) {
    u32x4 pk;
#pragma unroll
    for (int e = 0; e < 4; e++) {
      int j = q * 8 + e * 2;
      int c = cs * 32 + j;
      pk[e] = pk2((v[j] - mu) * rstd * w[c] + b[c],
                  (v[j + 1] - mu) * rstd * w[c + 1] + b[c + 1]);
    }
    tile[pxl * 16 + ((cs * 4 + q) ^ (pxl & 7))] = pk;
  }
  __syncthreads();
  u32x4* dst = (u32x4*)xnt + (size_t)(bi * HWSZ + p0) * 16;
  for (int it = 0; it < 4; it++) {
    int f = it * 256 + tid;
    int px = f >> 4, gg = f & 15;
    dst[f] = tile[px * 16 + (gg ^ (px & 7))];
  }
}

// ---------------- weight cast: wt[tap][co][ci] bf16 from kw[co][ci][tap] f32
__global__ __launch_bounds__(256) void k_wcast(const float* __restrict__ kw,
                                               short* __restrict__ wt) {
  int idx = blockIdx.x * 256 + threadIdx.x;  // 9*128*128
  if (idx >= 9 * 128 * 128) return;
  int ci = idx & 127, co = (idx >> 7) & 127, tap = idx >> 14;
  wt[idx] = f2bf(kw[(co * CC + ci) * 9 + tap]);
}

// ---------------- prep1: bf16 weight casts + LN-fold vectors + small transposes
__global__ __launch_bounds__(256) void k_prep1(const float* __restrict__ vw,
                                               const float* __restrict__ p1w,
                                               const float* __restrict__ lnw,
                                               const float* __restrict__ lnb,
                                               const float* __restrict__ p1b,
                                               const float* __restrict__ p2w,
                                               const float* __restrict__ qw,
                                               const float* __restrict__ a1w,
                                               const float* __restrict__ dww,
                                               short* __restrict__ vwb,
                                               short* __restrict__ w1p,
                                               short* __restrict__ p2wb,
                                               float* __restrict__ s1,
                                               float* __restrict__ s2f,
                                               float* __restrict__ qwt,
                                               float* __restrict__ a1wt,
                                               float* __restrict__ dwwt) {
  int idx = blockIdx.x * 256 + threadIdx.x;
  if (idx < 16384) vwb[idx] = f2bf(vw[idx]);
  int i2 = idx - 16384;
  if (i2 >= 0 && i2 < 32768) { int c = i2 & 127; w1p[i2] = f2bf(p1w[i2] * lnw[c]); }
  int i3 = idx - 49152;
  if (i3 >= 0 && i3 < 32768) p2wb[i3] = f2bf(p2w[i3]);
  int i4 = idx - 81920;
  if (i4 >= 0 && i4 < 256) {
    float a = 0.f, bb2 = 0.f;
    for (int c = 0; c < 128; c++) {
      a   += p1w[i4 * 128 + c] * lnw[c];
      bb2 += p1w[i4 * 128 + c] * lnb[c];
    }
    s1[i4] = a; s2f[i4] = bb2 + p1b[i4];
  }
  int i5 = idx - 82176;
  if (i5 >= 0 && i5 < 1152) { int tap = i5 >> 7, c = i5 & 127; qwt[i5] = qw[c * 9 + tap]; }
  int i6 = idx - 83328;
  if (i6 >= 0 && i6 < 1152) { int tap = i6 >> 7, c = i6 & 127; a1wt[i6] = a1w[c * 9 + tap]; }
  int i7 = idx - 84480;
  if (i7 >= 0 && i7 < 2304) { int tap = i7 / 256, c = i7 - tap * 256; dwwt[i7] = dww[c * 9 + tap]; }
}

// ---------------- prep2: M[b] = po @ blockdiag(attnA@attnK)  (128x128 bf16 per batch)
__global__ __launch_bounds__(256) void k_prep2(const float* __restrict__ po,
                                               const float* __restrict__ attnA,
                                               const float* __restrict__ attnK,
                                               short* __restrict__ Mb) {
  __shared__ float T[8][16][16];
  int b = blockIdx.x;
  int tid = threadIdx.x;
  for (int i = tid; i < 2048; i += 256) {
    int h = i >> 8, c = (i >> 4) & 15, cc = i & 15;
    float s = 0.f;
#pragma unroll
    for (int d = 0; d < 8; d++)
      s += attnA[((b * 8 + h) * 16 + c) * 8 + d] * attnK[((b * 8 + h) * 8 + d) * 16 + cc];
    T[h][c][cc] = s;
  }
  __syncthreads();
  for (int i = tid; i < 16384; i += 256) {
    int co = i >> 7, cj = i & 127, h = cj >> 4, cc = cj & 15;
    float s = 0.f;
#pragma unroll
    for (int c = 0; c < 16; c++) s += po[co * 128 + h * 16 + c] * T[h][c][cc];
    Mb[b * 16384 + i] = f2bf(s);
  }
}

// ---------------- K_DWSN: fused depthwise 3x3 s2 reflect for q AND a1
__global__ __launch_bounds__(256) void k_dwsn(const short* __restrict__ xnt,
                                              const float* __restrict__ qwt,
                                              const float* __restrict__ a1wt,
                                              short* __restrict__ qg,
                                              short* __restrict__ a1g) {
  int blk = blockIdx.x;                 // 1024 = b(4) x y(128) x xg(2)
  int xg = blk & 1, y = (blk >> 1) & 127, b = blk >> 8;
  int oct = threadIdx.x & 15, pxq = threadIdx.x >> 4;  // pxq 0..15
  int x0 = xg * 64 + pxq * 4;
  float aq[4][8], aa[4][8];
#pragma unroll
  for (int j = 0; j < 4; j++)
#pragma unroll
    for (int c = 0; c < 8; c++) { aq[j][c] = 0.f; aa[j][c] = 0.f; }
#pragma unroll
  for (int tap = 0; tap < 9; tap++) {
    int dy = tap / 3, dx = tap - 3 * dy;
    int ry = 2 * y + dy - 1; ry = ry < 0 ? -ry : ry;
    float4 wq0 = *(const float4*)(qwt + tap * 128 + oct * 8);
    float4 wq1 = *(const float4*)(qwt + tap * 128 + oct * 8 + 4);
    float4 wa0 = *(const float4*)(a1wt + tap * 128 + oct * 8);
    float4 wa1 = *(const float4*)(a1wt + tap * 128 + oct * 8 + 4);
#pragma unroll
    for (int jq = 0; jq < 4; jq++) {
      int ix = 2 * (x0 + jq) + dx - 1; ix = ix < 0 ? -ix : ix;
      short8 xv = *(const short8*)(xnt + (size_t)((b * HWSZ + ry * WW + ix) * CC) + oct * 8);
      float f0 = b2f(xv[0]), f1 = b2f(xv[1]), f2 = b2f(xv[2]), f3 = b2f(xv[3]);
      float f4 = b2f(xv[4]), f5 = b2f(xv[5]), f6 = b2f(xv[6]), f7 = b2f(xv[7]);
      aq[jq][0] += wq0.x * f0; aq[jq][1] += wq0.y * f1; aq[jq][2] += wq0.z * f2; aq[jq][3] += wq0.w * f3;
      aq[jq][4] += wq1.x * f4; aq[jq][5] += wq1.y * f5; aq[jq][6] += wq1.z * f6; aq[jq][7] += wq1.w * f7;
      aa[jq][0] += wa0.x * f0; aa[jq][1] += wa0.y * f1; aa[jq][2] += wa0.z * f2; aa[jq][3] += wa0.w * f3;
      aa[jq][4] += wa1.x * f4; aa[jq][5] += wa1.y * f5; aa[jq][6] += wa1.z * f6; aa[jq][7] += wa1.w * f7;
    }
  }
  int pb = y * 128 + x0;
#pragma unroll
  for (int j = 0; j < 8; j++) {
    s16x4 vq = { f2bf(aq[0][j]), f2bf(aq[1][j]), f2bf(aq[2][j]), f2bf(aq[3][j]) };
    s16x4 va = { f2bf(aa[0][j]), f2bf(aa[1][j]), f2bf(aa[2][j]), f2bf(aa[3][j]) };
    *(s16x4*)(qg  + (size_t)(b * CC + oct * 8 + j) * L4SZ + pb) = vq;
    *(s16x4*)(a1g + (size_t)(b * CC + oct * 8 + j) * L4SZ + pb) = va;
  }
}

// ---------------- K3: dense 3x3 s2 conv 128->128 via MFMA, bf16 out
__global__ __launch_bounds__(256) void k_kconv_mfma(const short* __restrict__ xnt,
                                                    const short* __restrict__ wt,
                                                    short* __restrict__ kg) {
  __shared__ short8 ldsb[1156];  // 289 pixels x 4 granules(8ci), granule-swizzled
  int blk = blockIdx.x;
  int bx = blk & 15, by = (blk >> 4) & 15, bi = blk >> 8;
  int r0 = by * 16 - 1, c0 = bx * 16 - 1;
  int lane = threadIdx.x & 63, wv = threadIdx.x >> 6;
  int px0 = wv * 16;
  int pxl = px0 + (lane & 15);
  int py = pxl >> 3, pxx = pxl & 7;
  int g = lane >> 4;
  f32x4 acc[8];
#pragma unroll
  for (int m = 0; m < 8; m++) acc[m] = (f32x4){0.f, 0.f, 0.f, 0.f};
  for (int ci0 = 0; ci0 < CC; ci0 += 32) {
    __syncthreads();
    for (int i = threadIdx.x; i < 1156; i += 256) {
      int p = i >> 2, gg = i & 3;
      int rr = p / 17, cc = p - rr * 17;
      int gr = r0 + rr; gr = gr < 0 ? -gr : gr;
      int gc = c0 + cc; gc = gc < 0 ? -gc : gc;
      int slot = gg ^ ((p >> 1) & 3);
      ldsb[p * 4 + slot] =
          *(const short8*)(xnt + (size_t)((bi * HWSZ + gr * WW + gc) * CC + ci0 + gg * 8));
    }
    __syncthreads();
#pragma unroll
    for (int tap = 0; tap < 9; tap++) {
      int dy = tap / 3, dx = tap - dy * 3;
      int p = (2 * py + dy) * 17 + 2 * pxx + dx;
      int slot = g ^ ((p >> 1) & 3);
      short8 bfrag = ldsb[p * 4 + slot];
      const short* wbase = wt + (tap * 128 + (lane & 15)) * 128 + ci0 + g * 8;
#pragma unroll
      for (int m = 0; m < 8; m++) {
        short8 afrag = *(const short8*)(wbase + m * 16 * 128);
        acc[m] = __builtin_amdgcn_mfma_f32_16x16x32_bf16(afrag, bfrag, acc[m], 0, 0, 0);
      }
    }
  }
  int oy = by * 8 + py, ox = bx * 8 + pxx;
  int rb = g * 4;
#pragma unroll
  for (int m = 0; m < 8; m++)
#pragma unroll
    for (int r = 0; r < 4; r++)
      kg[(size_t)(bi * CC + m * 16 + rb + r) * L4SZ + oy * W2 + ox] = f2bf(acc[m][r]);
}

// ---------------- K5: 1x1 conv 128->64 + bias (a2), bf16 in/out
__global__ __launch_bounds__(256) void k_a2(const short* __restrict__ a1g,
                                            const float* __restrict__ w,
                                            const float* __restrict__ bias,
                                            short* __restrict__ ab) {
  __shared__ float t[CC][64];
  int blk = blockIdx.x;
  int bi = blk >> 8;
  int p0 = (blk & 255) * 64;
  for (int i = threadIdx.x; i < CC * 64; i += 256) {
    int ci = i >> 6, px = i & 63;
    t[ci][px] = b2f(a1g[(size_t)(bi * CC + ci) * L4SZ + p0 + px]);
  }
  __syncthreads();
  int px = threadIdx.x & 63;
  int co0 = ((__builtin_amdgcn_readfirstlane((int)threadIdx.x)) >> 6) << 4;
  float acc[16];
#pragma unroll
  for (int j = 0; j < 16; j++) acc[j] = 0.f;
  for (int ci = 0; ci < CC; ci++) {
    float in = t[ci][px];
#pragma unroll
    for (int j = 0; j < 16; j++) acc[j] += w[(co0 + j) * CC + ci] * in;
  }
#pragma unroll
  for (int j = 0; j < 16; j++)
    ab[(size_t)(bi * 64 + co0 + j) * L4SZ + p0 + px] = f2bf(acc[j] + bias[co0 + j]);
}

// ---------------- K_GRAM: all attention dot products via MFMA
__global__ __launch_bounds__(256) void k_gram(const short* __restrict__ qg,
                                              const short* __restrict__ kg,
                                              const short* __restrict__ ag,
                                              float* __restrict__ partial) {
  __shared__ float red[4][1280];
  int blk = blockIdx.x;              // 256 = bh(32) x chunk(8)
  int bh = blk >> 3, chunk = blk & 7;
  int b = bh >> 3, h = bh & 7;
  int tid = threadIdx.x, lane = tid & 63, wv = tid >> 6;
  int cl = lane & 15, g = lane >> 4;
  const short* qb = qg + (size_t)(b * 128 + h * 16 + cl) * L4SZ;
  const short* kb = kg + (size_t)(b * 128 + h * 16 + cl) * L4SZ;
  const short* ar = ag + (size_t)(b * 64 + h * 8 + cl) * L4SZ;  // cl>=8 reads pad region
  int k0 = chunk * 2048 + wv * 512 + g * 8;
  f32x4 t0 = {0,0,0,0}, t1 = {0,0,0,0}, t2 = {0,0,0,0}, t3 = {0,0,0,0}, t4 = {0,0,0,0};
#pragma unroll 4
  for (int ks = 0; ks < 16; ks++) {
    int ko = k0 + ks * 32;
    short8 fq = *(const short8*)(qb + ko);
    short8 fk = *(const short8*)(kb + ko);
    short8 fa = *(const short8*)(ar + ko);
    t0 = __builtin_amdgcn_mfma_f32_16x16x32_bf16(fq, fa, t0, 0, 0, 0);
    t1 = __builtin_amdgcn_mfma_f32_16x16x32_bf16(fa, fk, t1, 0, 0, 0);
    t2 = __builtin_amdgcn_mfma_f32_16x16x32_bf16(fq, fq, t2, 0, 0, 0);
    t3 = __builtin_amdgcn_mfma_f32_16x16x32_bf16(fk, fk, t3, 0, 0, 0);
    t4 = __builtin_amdgcn_mfma_f32_16x16x32_bf16(fa, fa, t4, 0, 0, 0);
  }
#pragma unroll
  for (int r = 0; r < 4; r++) {
    int flat = (g * 4 + r) * 16 + cl;
    red[wv][flat]        = t0[r];
    red[wv][256 + flat]  = t1[r];
    red[wv][512 + flat]  = t2[r];
    red[wv][768 + flat]  = t3[r];
    red[wv][1024 + flat] = t4[r];
  }
  __syncthreads();
  float* po = partial + (size_t)(bh * 8 + chunk) * 1280;
  for (int i = tid; i < 1280; i += 256)
    po[i] = red[0][i] + red[1][i] + red[2][i] + red[3][i];
}

// ---------------- K6b: reduce partials + softmax
__global__ __launch_bounds__(64) void k_softmax2(const float* __restrict__ partial,
                                                 const float* __restrict__ tA,
                                                 const float* __restrict__ tV,
                                                 float* __restrict__ attnA,
                                                 float* __restrict__ attnK) {
  __shared__ float S[1280];
  int bh = blockIdx.x;            // 32
  int h = bh & 7;
  for (int i = threadIdx.x; i < 1280; i += 64) {
    float s = 0.f;
    for (int c = 0; c < 8; c++) s += partial[(size_t)(bh * 8 + c) * 1280 + i];
    S[i] = s;
  }
  __syncthreads();
  float ta = tA[h], tv = tV[h];
  if (threadIdx.x < 16) {
    int c = threadIdx.x;
    float nq = fmaxf(sqrtf(S[512 + c * 17]), 1e-12f);
    float lg[8]; float m = -1e30f;
#pragma unroll
    for (int e = 0; e < 8; e++) {
      float na = fmaxf(sqrtf(S[1024 + e * 17]), 1e-12f);
      lg[e] = S[c * 16 + e] / (nq * na) * ta;
      m = fmaxf(m, lg[e]);
    }
    float sum = 0.f;
#pragma unroll
    for (int e = 0; e < 8; e++) { lg[e] = expf(lg[e] - m); sum += lg[e]; }
    float inv = 1.f / sum;
#pragma unroll
    for (int e = 0; e < 8; e++) attnA[(bh * 16 + c) * 8 + e] = lg[e] * inv;
  } else if (threadIdx.x < 24) {
    int e = threadIdx.x - 16;
    float na = fmaxf(sqrtf(S[1024 + e * 17]), 1e-12f);
    float lg[16]; float m = -1e30f;
#pragma unroll
    for (int c = 0; c < 16; c++) {
      float nk = fmaxf(sqrtf(S[768 + c * 17]), 1e-12f);
      lg[c] = S[256 + e * 16 + c] / (na * nk) * tv;
      m = fmaxf(m, lg[c]);
    }
    float sum = 0.f;
#pragma unroll
    for (int c = 0; c < 16; c++) { lg[c] = expf(lg[c] - m); sum += lg[c]; }
    float inv = 1.f / sum;
#pragma unroll
    for (int c = 0; c < 16; c++) attnK[(bh * 8 + e) * 16 + c] = lg[c] * inv;
  }
}

// ---------------- K_VX2: fused v-conv + illu + attn-apply (M@v) + residual + LN2 stats
__global__ __launch_bounds__(256) void k_vx2(const short* __restrict__ xnt,
                                             const float* __restrict__ illu,
                                             const float* __restrict__ x,
                                             const short* __restrict__ vwb,
                                             const short* __restrict__ Mb,
                                             u32x4* __restrict__ x2n4,
                                             float* __restrict__ mu,
                                             float* __restrict__ rs) {
  __shared__ unsigned lds[4608];
  int blk = blockIdx.x;
  int bi = blk >> 10, p0 = (blk & 1023) * 64;
  int tid = threadIdx.x, lane = tid & 63, wv = tid >> 6;
  int cl = lane & 15, g = lane >> 4;
  int px = wv * 16 + cl;
  const u32x4* xsrc = (const u32x4*)(xnt + ((size_t)(bi * HWSZ + p0) << 7));
  for (int it = 0; it < 4; it++) {
    int idx = it * 256 + tid;
    int pp = idx >> 4, gg = idx & 15;
    u32x4 v = xsrc[pp * 16 + gg];
    ((u32x4*)lds)[pp * 16 + (gg ^ (pp & 7))] = v;
  }
  __syncthreads();
  f32x4 acc[8];
#pragma unroll
  for (int m = 0; m < 8; m++) acc[m] = (f32x4){0.f, 0.f, 0.f, 0.f};
#pragma unroll
  for (int kc = 0; kc < 4; kc++) {
    short8 bf = *(const short8*)((const short*)lds + px * 128 + (((kc * 4 + g) ^ (px & 7)) * 8));
#pragma unroll
    for (int m = 0; m < 8; m++) {
      short8 af = *(const short8*)(vwb + (m * 16 + cl) * 128 + kc * 32 + g * 8);
      acc[m] = __builtin_amdgcn_mfma_f32_16x16x32_bf16(af, bf, acc[m], 0, 0, 0);
    }
  }
  __syncthreads();
#pragma unroll
  for (int m = 0; m < 8; m++) {
    int cob = m * 16 + g * 4;
    float v0 = acc[m][0] * illu[(size_t)(bi * CC + cob + 0) * HWSZ + p0 + px];
    float v1 = acc[m][1] * illu[(size_t)(bi * CC + cob + 1) * HWSZ + p0 + px];
    float v2 = acc[m][2] * illu[(size_t)(bi * CC + cob + 2) * HWSZ + p0 + px];
    float v3 = acc[m][3] * illu[(size_t)(bi * CC + cob + 3) * HWSZ + p0 + px];
    int gi = 2 * m + (g >> 1);
    unsigned* dst = lds + px * 64 + ((gi ^ (px & 7)) << 2) + (g & 1) * 2;
    dst[0] = pk2(v0, v1);
    dst[1] = pk2(v2, v3);
  }
  __syncthreads();
  f32x4 acc2[8];
#pragma unroll
  for (int m = 0; m < 8; m++) acc2[m] = (f32x4){0.f, 0.f, 0.f, 0.f};
  const short* Mbb = Mb + bi * 16384;
#pragma unroll
  for (int kc = 0; kc < 4; kc++) {
    short8 bf = *(const short8*)((const short*)lds + px * 128 + (((kc * 4 + g) ^ (px & 7)) * 8));
#pragma unroll
    for (int m = 0; m < 8; m++) {
      short8 af = *(const short8*)(Mbb + (m * 16 + cl) * 128 + kc * 32 + g * 8);
      acc2[m] = __builtin_amdgcn_mfma_f32_16x16x32_bf16(af, bf, acc2[m], 0, 0, 0);
    }
  }
  float s = 0.f, s2 = 0.f;
  unsigned xp[16];
#pragma unroll
  for (int m = 0; m < 8; m++) {
    float tv[4];
#pragma unroll
    for (int r = 0; r < 4; r++) {
      int co = m * 16 + g * 4 + r;
      size_t gi = (size_t)(bi * CC + co) * HWSZ + p0 + px;
      float t = x[gi] + acc2[m][r];
      tv[r] = t; s += t; s2 += t * t;
    }
    xp[2 * m]     = pk2(tv[0], tv[1]);
    xp[2 * m + 1] = pk2(tv[2], tv[3]);
  }
  s  += __shfl_xor(s, 16);  s  += __shfl_xor(s, 32);
  s2 += __shfl_xor(s2, 16); s2 += __shfl_xor(s2, 32);
  float muv = s * (1.f / 128.f);
  float rsv = rsqrtf(s2 * (1.f / 128.f) - muv * muv + 1e-5f);
  if (g == 0) { mu[bi * HWSZ + p0 + px] = muv; rs[bi * HWSZ + p0 + px] = rsv; }
  __syncthreads();
#pragma unroll
  for (int m = 0; m < 8; m++) {
    lds[px * 68 + m * 8 + g * 2 + 0] = xp[2 * m];
    lds[px * 68 + m * 8 + g * 2 + 1] = xp[2 * m + 1];
  }
  __syncthreads();
  u32x4* dst4 = x2n4 + (size_t)(bi * HWSZ + p0) * 16;
  for (int it = 0; it < 4; it++) {
    int flat = it * 256 + tid;
    int pp = flat >> 4, j = flat & 15;
    dst4[flat] = *(const u32x4*)(lds + pp * 68 + j * 4);
  }
}

// ---------------- K_P1: LN2-folded p1 GEMM (256 mid x 64 px, K=128), bf16 NHWC y1 out
__global__ __launch_bounds__(256) void k_p1(const u32x4* __restrict__ x2n4,
                                            const short* __restrict__ w1p,
                                            const float* __restrict__ s1,
                                            const float* __restrict__ s2f,
                                            const float* __restrict__ mu,
                                            const float* __restrict__ rs,
                                            u32x4* __restrict__ y1n4) {
  __shared__ u32x4 bt[1024];     // [kg][px ^ kg]  16KB
  __shared__ u32x4 olds[2048];   // out bounce [px][32 granules swizzled]  32KB
  int blk = blockIdx.x;          // 4096 = b(4) x 1024 tiles of 64 px
  int bi = blk >> 10, p0 = (blk & 1023) * 64;
  int tid = threadIdx.x, lane = tid & 63, wv = tid >> 6;
  int cl = lane & 15, g = lane >> 4;
  for (int f = tid; f < 1024; f += 256) {
    int px = f >> 4, kg = f & 15;
    bt[kg * 64 + (px ^ kg)] = x2n4[(size_t)(bi * HWSZ + p0 + px) * 16 + kg];
  }
  __syncthreads();
  f32x4 acc[4][4];
#pragma unroll
  for (int mt = 0; mt < 4; mt++)
#pragma unroll
    for (int n = 0; n < 4; n++) acc[mt][n] = (f32x4){0.f, 0.f, 0.f, 0.f};
#pragma unroll
  for (int kc = 0; kc < 4; kc++) {
    short8 bfr[4];
#pragma unroll
    for (int n = 0; n < 4; n++) {
      int px = n * 16 + cl, kgi = kc * 4 + g;
      bfr[n] = __builtin_bit_cast(short8, bt[kgi * 64 + (px ^ kgi)]);
    }
#pragma unroll
    for (int mt = 0; mt < 4; mt++) {
      short8 af = *(const short8*)(w1p + (wv * 64 + mt * 16 + cl) * 128 + kc * 32 + g * 8);
#pragma unroll
      for (int n = 0; n < 4; n++)
        acc[mt][n] = __builtin_amdgcn_mfma_f32_16x16x32_bf16(af, bfr[n], acc[mt][n], 0, 0, 0);
    }
  }
  float muv[4], rsv[4];
#pragma unroll
  for (int n = 0; n < 4; n++) {
    muv[n] = mu[bi * HWSZ + p0 + n * 16 + cl];
    rsv[n] = rs[bi * HWSZ + p0 + n * 16 + cl];
  }
#pragma unroll
  for (int mt = 0; mt < 4; mt++) {
    int mid = wv * 64 + mt * 16 + g * 4;
    float4 s1v = *(const float4*)(s1 + mid);
    float4 s2v = *(const float4*)(s2f + mid);
    int gi = wv * 8 + mt * 2 + (g >> 1);
#pragma unroll
    for (int n = 0; n < 4; n++) {
      int px = n * 16 + cl;
      float y0 = rsv[n] * (acc[mt][n][0] - muv[n] * s1v.x) + s2v.x;
      float y1 = rsv[n] * (acc[mt][n][1] - muv[n] * s1v.y) + s2v.y;
      float y2 = rsv[n] * (acc[mt][n][2] - muv[n] * s1v.z) + s2v.z;
      float y3 = rsv[n] * (acc[mt][n][3] - muv[n] * s1v.w) + s2v.w;
      unsigned* dp = (unsigned*)&olds[px * 32 + (gi ^ (px & 7))] + (g & 1) * 2;
      dp[0] = pk2(y0, y1);
      dp[1] = pk2(y2, y3);
    }
  }
  __syncthreads();
  u32x4* dst = y1n4 + (size_t)(bi * HWSZ + p0) * 32;
  for (int it = 0; it < 8; it++) {
    int f = it * 256 + tid;
    int px = f >> 5, gi = f & 31;
    dst[f] = olds[px * 32 + (gi ^ (px & 7))];
  }
}

// ---------------- K_FFN2: dw3x3 + bias + relu (VALU) + p2 (MFMA) + bf16 residual
__global__ __launch_bounds__(256) void k_ffn2(const u32x4* __restrict__ y1n4,
                                              const float* __restrict__ dwwt,
                                              const float* __restrict__ dwb,
                                              const short* __restrict__ p2wb,
                                              const float* __restrict__ p2b,
                                              const u32x4* __restrict__ x2n4,
                                              float* __restrict__ out) {
  __shared__ u32x4 ylds[1600];   // [100 px][16 granules] XOR-swizzled  25.6KB
  __shared__ u32x4 dwt[1024];    // [64 px][16 granules] XOR-swizzled   16KB
  int blk = blockIdx.x;          // 4096 = b(4) x ty(32) x tx(32)
  int tx = blk & 31, ty = (blk >> 5) & 31, b = blk >> 10;
  int r0 = ty * 8 - 1, c0 = tx * 8 - 1;
  int tid = threadIdx.x, lane = tid & 63, wv = tid >> 6;
  int cl = lane & 15, g = lane >> 4;
  int pp = tid & 63;
  int qy = pp >> 3, qx = pp & 7;
  f32x4 acc[2][4];
#pragma unroll
  for (int mt = 0; mt < 2; mt++)
#pragma unroll
    for (int n = 0; n < 4; n++) acc[mt][n] = (f32x4){0.f, 0.f, 0.f, 0.f};
  for (int ch = 0; ch < 2; ch++) {
    if (ch) __syncthreads();
    for (int i = tid; i < 1600; i += 256) {
      int p = i >> 4, gg = i & 15;
      int rr = p / 10, cc = p - rr * 10;
      int gr = r0 + rr, gc = c0 + cc;
      u32x4 v = (u32x4){0u, 0u, 0u, 0u};
      if (gr >= 0 && gr < HH && gc >= 0 && gc < WW)
        v = y1n4[(size_t)(b * HWSZ + gr * WW + gc) * 32 + ch * 16 + gg];
      ylds[p * 16 + (gg ^ (p & 7))] = v;
    }
    __syncthreads();
    // depthwise 3x3 + bias + relu: thread -> pixel pp, mid chunk wv*32..+32
    float sdw[32];
#pragma unroll
    for (int j = 0; j < 32; j++) sdw[j] = 0.f;
#pragma unroll
    for (int tap = 0; tap < 9; tap++) {
      int dy = tap / 3, dx = tap - 3 * dy;
      int p = (qy + dy) * 10 + qx + dx;
      const float* wp = dwwt + tap * 256 + ch * 128 + wv * 32;
#pragma unroll
      for (int q = 0; q < 4; q++) {
        u32x4 vv = ylds[p * 16 + ((wv * 4 + q) ^ (p & 7))];
        sdw[q * 8 + 0] += wp[q * 8 + 0] * bflo(vv.x);
        sdw[q * 8 + 1] += wp[q * 8 + 1] * bfhi(vv.x);
        sdw[q * 8 + 2] += wp[q * 8 + 2] * bflo(vv.y);
        sdw[q * 8 + 3] += wp[q * 8 + 3] * bfhi(vv.y);
        sdw[q * 8 + 4] += wp[q * 8 + 4] * bflo(vv.z);
        sdw[q * 8 + 5] += wp[q * 8 + 5] * bfhi(vv.z);
        sdw[q * 8 + 6] += wp[q * 8 + 6] * bflo(vv.w);
        sdw[q * 8 + 7] += wp[q * 8 + 7] * bfhi(vv.w);
      }
    }
    const float* db = dwb + ch * 128 + wv * 32;
#pragma unroll
    for (int q = 0; q < 4; q++) {
      u32x4 pkv;
      pkv.x = pk2(fmaxf(sdw[q * 8 + 0] + db[q * 8 + 0], 0.f), fmaxf(sdw[q * 8 + 1] + db[q * 8 + 1], 0.f));
      pkv.y = pk2(fmaxf(sdw[q * 8 + 2] + db[q * 8 + 2], 0.f), fmaxf(sdw[q * 8 + 3] + db[q * 8 + 3], 0.f));
      pkv.z = pk2(fmaxf(sdw[q * 8 + 4] + db[q * 8 + 4], 0.f), fmaxf(sdw[q * 8 + 5] + db[q * 8 + 5], 0.f));
      pkv.w = pk2(fmaxf(sdw[q * 8 + 6] + db[q * 8 + 6], 0.f), fmaxf(sdw[q * 8 + 7] + db[q * 8 + 7], 0.f));
      dwt[pp * 16 + ((wv * 4 + q) ^ (pp & 7))] = pkv;
    }
    __syncthreads();
    // p2 partial: wave -> 32 co, K = this chunk's 128 mid
#pragma unroll
    for (int kc = 0; kc < 4; kc++) {
      short8 af0 = *(const short8*)(p2wb + (wv * 32 + cl) * 256 + ch * 128 + kc * 32 + g * 8);
      short8 af1 = *(const short8*)(p2wb + (wv * 32 + 16 + cl) * 256 + ch * 128 + kc * 32 + g * 8);
#pragma unroll
      for (int n = 0; n < 4; n++) {
        int px = n * 16 + cl;
        short8 bf = __builtin_bit_cast(short8, dwt[px * 16 + ((kc * 4 + g) ^ (px & 7))]);
        acc[0][n] = __builtin_amdgcn_mfma_f32_16x16x32_bf16(af0, bf, acc[0][n], 0, 0, 0);
        acc[1][n] = __builtin_amdgcn_mfma_f32_16x16x32_bf16(af1, bf, acc[1][n], 0, 0, 0);
      }
    }
  }
  // epilogue: out = bf16(x2) + p2 + p2b
#pragma unroll
  for (int mt = 0; mt < 2; mt++) {
    int cob = wv * 32 + mt * 16 + g * 4;
    float pb0 = p2b[cob + 0], pb1 = p2b[cob + 1], pb2 = p2b[cob + 2], pb3 = p2b[cob + 3];
#pragma unroll
    for (int n = 0; n < 4; n++) {
      int px = n * 16 + cl;
      int oy = ty * 8 + (px >> 3), ox = tx * 8 + (px & 7);
      size_t gp = (size_t)b * HWSZ + oy * WW + ox;
      const unsigned* xr = (const unsigned*)(x2n4 + gp * 16 + (cob >> 3));
      unsigned xa = xr[(g & 1) * 2 + 0], xb2 = xr[(g & 1) * 2 + 1];
      size_t gi = (size_t)(b * CC + cob) * HWSZ + oy * WW + ox;
      out[gi]             = bflo(xa)  + acc[mt][n][0] + pb0;
      out[gi + HWSZ]      = bfhi(xa)  + acc[mt][n][1] + pb1;
      out[gi + 2 * HWSZ]  = bflo(xb2) + acc[mt][n][2] + pb2;
      out[gi + 3 * HWSZ]  = bfhi(xb2) + acc[mt][n][3] + pb3;
    }
  }
}

extern "C" void kernel_launch(void* const* d_in, const int* in_sizes, int n_in,
                              void* d_out, int out_size, void* d_ws, size_t ws_size,
                              hipStream_t stream) {
  const float* x    = (const float*)d_in[0];
  const float* illu = (const float*)d_in[1];
  const float* ln1w = (const float*)d_in[2];
  const float* ln1b = (const float*)d_in[3];
  const float* qw   = (const float*)d_in[4];
  const float* kw   = (const float*)d_in[5];
  const float* vw   = (const float*)d_in[6];
  const float* a1w  = (const float*)d_in[7];
  const float* a2w  = (const float*)d_in[8];
  const float* a2b  = (const float*)d_in[9];
  const float* tA   = (const float*)d_in[10];
  const float* tV   = (const float*)d_in[11];
  const float* pow_ = (const float*)d_in[12];
  const float* ln2w = (const float*)d_in[13];
  const float* ln2b = (const float*)d_in[14];
  const float* p1w  = (const float*)d_in[15];
  const float* p1b  = (const float*)d_in[16];
  const float* dww  = (const float*)d_in[17];
  const float* dwb  = (const float*)d_in[18];
  const float* p2w  = (const float*)d_in[19];
  const float* p2b  = (const float*)d_in[20];
  float* out = (float*)d_out;

  // workspace layout (float offsets); peak concurrent ~204MB
  float* ws    = (float*)d_ws;
  u32x4* x2n4  = (u32x4*)ws;                       // [0 .. 16,777,216)
  float* mu    = ws + 16777216;                    // 262,144
  float* rs    = ws + 17039360;                    // 262,144
  float* attnA = ws + 17301504;                    // 4,096
  float* attnK = ws + 17305600;                    // 4,096
  short* vwb   = (short*)(ws + 17309696);          // 16,384 sh
  short* w1p   = (short*)(ws + 17317888);          // 32,768 sh
  short* p2wb  = (short*)(ws + 17334272);          // 32,768 sh
  short* Mb    = (short*)(ws + 17350656);          // 65,536 sh
  float* s1    = ws + 17383424;                    // 256
  float* s2f   = ws + 17383680;                    // 256
  short* wt    = (short*)(ws + 17383936);          // 147,456 sh
  float* qwt   = ws + 17457664;                    // 1,152
  float* a1wt  = ws + 17458816;                    // 1,152
  float* dwwt  = ws + 17459968;                    // 2,304 -> ends 17,462,272
  // y1n region (134MB) aliases the phase-A/B buffers below:
  u32x4* y1n4  = (u32x4*)(ws + 17462272);          // [17,462,272 .. 51,016,704)
  short* xnt   = (short*)(ws + 17462272);          // 33,554,432 sh
  short* qg    = (short*)(ws + 34239488);          // 8,388,608 sh
  short* kgb   = (short*)(ws + 38433792);          // 8,388,608 sh
  short* a1g   = (short*)(ws + 42628096);          // 8,388,608 sh
  short* ab    = (short*)(ws + 46822400);          // 4,194,304 sh
  float* partial = ws + 48919552;                  // 327,680 (also gram over-read pad)

  k_ln1<<<4096, 256, 0, stream>>>(x, ln1w, ln1b, xnt);
  k_wcast<<<576, 256, 0, stream>>>(kw, wt);
  k_prep1<<<340, 256, 0, stream>>>(vw, p1w, ln2w, ln2b, p1b, p2w, qw, a1w, dww,
                                   vwb, w1p, p2wb, s1, s2f, qwt, a1wt, dwwt);
  k_dwsn<<<1024, 256, 0, stream>>>(xnt, qwt, a1wt, qg, a1g);
  k_kconv_mfma<<<1024, 256, 0, stream>>>(xnt, wt, kgb);
  k_a2<<<1024, 256, 0, stream>>>(a1g, a2w, a2b, ab);
  k_gram<<<256, 256, 0, stream>>>(qg, kgb, ab, partial);
  k_softmax2<<<32, 64, 0, stream>>>(partial, tA, tV, attnA, attnK);
  k_prep2<<<4, 256, 0, stream>>>(pow_, attnA, attnK, Mb);
  k_vx2<<<4096, 256, 0, stream>>>(xnt, illu, x, vwb, Mb, x2n4, mu, rs);
  k_p1<<<4096, 256, 0, stream>>>(x2n4, w1p, s1, s2f, mu, rs, y1n4);
  k_ffn2<<<4096, 256, 0, stream>>>(y1n4, dwwt, dwb, p2wb, p2b, x2n4, out);
}